// Round 13
// baseline (195.084 us; speedup 1.0000x reference)
//
#include <hip/hip_runtime.h>

// RelGraphConv basis-decomposition forward, MI355X.
//
// Input-space reformulation:
//   g[d, b, :] = sum_{e: dst_e = d} w_comp[et_e, b] * feat[src_e, :]   (b = 0,1)
//   out[d]     = g[d,0] @ V0 + g[d,1] @ V1 + feat[d] @ W_loop + bias
//
// Pipeline:
//   k_cvt (feat -> bf16) ; memset bcnt -> k_bhist -> k_bscan -> k_bscatter
//   (coarse 391-bucket multisplit) -> k_fine (per-bucket exact per-node CSR)
//   -> k_gather_post (FUSED gather + dense [g0,g1,feat](192)->64 GEMM).
//
// r13 gather: quarter scheme on the r12 skeleton. Each lane loads uint2
// (4 bf16 cols); quarter q = lane>>4 picks one of 4 edges; one wave-load
// covers 4 edges (VMEM instr/edge 0.25 vs 1.0 in r12). Batches of 8
// entries = 2 quarter-groups -> 8 loads keep 32 edges in flight.
// Spill discipline (r8/r9 lesson): (512,4) = 128-VGPR cap, small state.

constexpr int N_NODES  = 100000;
constexpr int N_EDGES  = 1600000;
constexpr int IN_FEAT  = 64;
constexpr int OUT_FEAT = 64;

constexpr int BN = 256;                                // nodes per bucket
constexpr int NB = (N_NODES + BN - 1) / BN;            // 391 buckets
constexpr int SC_CHUNK = 4096;                         // edges per scatter block

constexpr int NODES_PER_GRP = 8;
constexpr int N_GRP  = N_NODES / NODES_PER_GRP;        // 12500 (exact)

// entry pack: dst_low(8) | src(17) | etype(6)
__device__ __forceinline__ unsigned pack_entry(int d, int s, int r) {
    return (unsigned)(d & (BN - 1)) | ((unsigned)s << 8) | ((unsigned)r << 25);
}

__device__ __forceinline__ unsigned bf16_rne(float f) {
    unsigned b = __float_as_uint(f);
    b += 0x7fffu + ((b >> 16) & 1u);
    return b >> 16;
}

// ---------------------------------------------------------------- f32->bf16
__global__ __launch_bounds__(256) void k_cvt(const float* __restrict__ feat,
                                             unsigned* __restrict__ fbf) {
    const int total = N_NODES * 16;    // float4 count
    const float4* __restrict__ f4 = (const float4*)feat;
    uint2* __restrict__ o2 = (uint2*)fbf;
    for (int i = blockIdx.x * 256 + threadIdx.x; i < total; i += gridDim.x * 256) {
        const float4 f = f4[i];
        uint2 o;
        o.x = bf16_rne(f.x) | (bf16_rne(f.y) << 16);
        o.y = bf16_rne(f.z) | (bf16_rne(f.w) << 16);
        o2[i] = o;
    }
}

// ---------------------------------------------------------------- coarse hist
__global__ __launch_bounds__(256) void k_bhist(const int* __restrict__ dst,
                                               int* __restrict__ bcnt) {
    __shared__ int hist[NB];
    const int t = threadIdx.x;
    for (int i = t; i < NB; i += 256) hist[i] = 0;
    __syncthreads();
    const int cbase = blockIdx.x * 2048;
    #pragma unroll
    for (int k = 0; k < 8; ++k) {
        const int e = cbase + k * 256 + t;
        if (e < N_EDGES) atomicAdd(&hist[dst[e] >> 8], 1);
    }
    __syncthreads();
    for (int i = t; i < NB; i += 256)
        if (hist[i]) atomicAdd(&bcnt[i], hist[i]);
}

// ---------------------------------------------------------------- coarse scan
__global__ __launch_bounds__(512) void k_bscan(const int* __restrict__ bcnt,
                                               int* __restrict__ bbase,
                                               int* __restrict__ bcursor) {
    __shared__ int part[512];
    const int t = threadIdx.x;
    const int v = (t < NB) ? bcnt[t] : 0;
    part[t] = v;
    __syncthreads();
    for (int d = 1; d < 512; d <<= 1) {
        const int u = (t >= d) ? part[t - d] : 0;
        __syncthreads();
        part[t] += u;
        __syncthreads();
    }
    if (t < NB) {
        const int ex = part[t] - v;   // exclusive
        bbase[t] = ex;
        bcursor[t] = ex;
    }
    if (t == 0) bbase[NB] = N_EDGES;
}

// ---------------------------------------------------------------- multisplit
__global__ __launch_bounds__(256) void k_bscatter(const int* __restrict__ src,
                                                  const int* __restrict__ dst,
                                                  const int* __restrict__ et,
                                                  int* __restrict__ bcursor,
                                                  unsigned* __restrict__ sorted_c) {
    __shared__ int hist[NB], gb[NB], lcur[NB];
    const int t = threadIdx.x;
    const int cbase = blockIdx.x * SC_CHUNK;
    for (int i = t; i < NB; i += 256) { hist[i] = 0; lcur[i] = 0; }
    __syncthreads();
    #pragma unroll 1
    for (int k = 0; k < SC_CHUNK / 256; ++k) {
        const int e = cbase + k * 256 + t;
        if (e < N_EDGES) atomicAdd(&hist[dst[e] >> 8], 1);
    }
    __syncthreads();
    for (int i = t; i < NB; i += 256) {
        const int c = hist[i];
        gb[i] = c ? atomicAdd(&bcursor[i], c) : 0;
    }
    __syncthreads();
    #pragma unroll 1
    for (int k = 0; k < SC_CHUNK / 256; ++k) {
        const int e = cbase + k * 256 + t;
        if (e < N_EDGES) {
            const int d = dst[e];
            const int bkt = d >> 8;
            const int r = atomicAdd(&lcur[bkt], 1);
            sorted_c[gb[bkt] + r] = pack_entry(d, src[e], et[e]);
        }
    }
}

// ---------------------------------------------------------------- fine CSR
__global__ __launch_bounds__(256) void k_fine(const unsigned* __restrict__ sorted_c,
                                              const int* __restrict__ bbase,
                                              int* __restrict__ offsets,
                                              unsigned* __restrict__ sorted_f) {
    __shared__ int cnt[BN];
    __shared__ int part[BN];
    __shared__ int cur[BN];
    const int t = threadIdx.x;
    const int b = blockIdx.x;
    cnt[t] = 0;
    __syncthreads();
    const int base = bbase[b];
    const int end  = bbase[b + 1];
    for (int k = base + t; k < end; k += 256)
        atomicAdd(&cnt[sorted_c[k] & (BN - 1)], 1);
    __syncthreads();
    const int v = cnt[t];
    part[t] = v;
    __syncthreads();
    for (int d = 1; d < BN; d <<= 1) {
        const int u = (t >= d) ? part[t - d] : 0;
        __syncthreads();
        part[t] += u;
        __syncthreads();
    }
    const int node = b * BN + t;
    const int off = base + part[t] - v;   // exclusive within bucket
    if (node < N_NODES) offsets[node] = off;
    cur[t] = off;
    if (b == NB - 1 && t == 0) offsets[N_NODES] = N_EDGES;
    __syncthreads();
    for (int k = base + t; k < end; k += 256) {
        const unsigned en = sorted_c[k];
        const int pos = atomicAdd(&cur[en & (BN - 1)], 1);
        sorted_f[pos] = en;
    }
}

// ---------------------------------------------------------------- fused
// 512 threads = 8 waves; 12500 blocks, one group of 8 nodes each.
// Phase 1 (quarter scheme): wave w gathers node grp*8+w. Quarter q=lane>>4
//   picks the edge within each 4-group; sl=lane&15 picks the uint2 (4 bf16
//   cols). One dwordx2 wave-load covers 4 edges. Cross-quarter shfl_xor
//   (16,32) reduce; lanes<16 write g0/g1 as float4.
// Phase 2: thread (seg=w, col=lane) does the 24-row K-segment of the
//   192->64 GEMM for all 8 nodes; LDS partial reduce; coalesced out.
__global__ __launch_bounds__(512, 4) void k_gather_post(
    const int*      __restrict__ offsets,
    const unsigned* __restrict__ sorted_f,
    const float*    __restrict__ w_comp,      // (64, 2)
    const float*    __restrict__ feat,        // (N, 64) f32 (self-loop row)
    const unsigned* __restrict__ fbf,         // (N, 64) bf16 = 16 uint2/row
    const float*    __restrict__ weight,      // (2, 64, 64) = Wcat rows 0..127
    const float*    __restrict__ loop_weight, // (64, 64)    = Wcat rows 128..191
    const float*    __restrict__ h_bias,      // (64,)
    float*          __restrict__ out)         // (N, 64)
{
    __shared__ float4 Lin4[NODES_PER_GRP][48];  // [node][192 f32]: g0|g1|feat
    __shared__ float  ps[8][NODES_PER_GRP][64]; // [seg][node][col]
    __shared__ float2 wcl[64];                  // w_comp copy
    float* Lin = (float*)Lin4;

    const int tid  = threadIdx.x;
    const int lane = tid & 63;                // = col in phase 2
    const int w    = tid >> 6;                // wave = node slot = K-seg
    const int q    = lane >> 4;               // edge slot within 4-group
    const int sl   = lane & 15;               // uint2 column within row

    // Wcat (= [V0; V1; W_loop]) column segment, rows w*24..w*24+23.
    float wcol[24];
    #pragma unroll
    for (int i = 0; i < 24; ++i) {
        const int r = w * 24 + i;
        wcol[i] = (r < 128) ? weight[r * 64 + lane]
                            : loop_weight[(r - 128) * 64 + lane];
    }
    const float bias = h_bias[lane];
    if (tid < 64) wcl[tid] = ((const float2*)w_comp)[tid];
    const uint2* __restrict__ fb2 = (const uint2*)fbf;  // row = 16 uint2
    __syncthreads();   // wcl visible

    const int grp = blockIdx.x;

    // ---- Phase 1: each wave gathers its node (quarter scheme) ----
    {
        const int n = __builtin_amdgcn_readfirstlane(grp * 8 + w);
        const int start = __builtin_amdgcn_readfirstlane(offsets[n]);
        const int end   = __builtin_amdgcn_readfirstlane(offsets[n + 1]);
        const float fv = feat[(size_t)n * 64 + lane];

        float a0 = 0.f, a1 = 0.f, a2 = 0.f, a3 = 0.f;
        float b0 = 0.f, b1 = 0.f, b2 = 0.f, b3 = 0.f;
        int k = start;
        for (; k + 7 < end; k += 8) {
            unsigned p[8];
            #pragma unroll
            for (int i = 0; i < 8; ++i) p[i] = sorted_f[k + i];   // uniform -> s_load
            #pragma unroll
            for (int gi = 0; gi < 2; ++gi) {
                unsigned pa = p[gi * 4];
                pa = (q == 1) ? p[gi * 4 + 1] : pa;
                pa = (q == 2) ? p[gi * 4 + 2] : pa;
                pa = (q == 3) ? p[gi * 4 + 3] : pa;
                const int s = (pa >> 8) & 0x1FFFF;
                const uint2 d = fb2[(size_t)s * 16 + sl];
                const float2 c = wcl[pa >> 25];
                const float f0 = __uint_as_float(d.x << 16);
                const float f1 = __uint_as_float(d.x & 0xffff0000u);
                const float f2 = __uint_as_float(d.y << 16);
                const float f3 = __uint_as_float(d.y & 0xffff0000u);
                a0 = fmaf(c.x, f0, a0); a1 = fmaf(c.x, f1, a1);
                a2 = fmaf(c.x, f2, a2); a3 = fmaf(c.x, f3, a3);
                b0 = fmaf(c.y, f0, b0); b1 = fmaf(c.y, f1, b1);
                b2 = fmaf(c.y, f2, b2); b3 = fmaf(c.y, f3, b3);
            }
        }
        for (; k < end; k += 4) {                 // clamped 4-group tail
            const int rem = end - k;
            const int idx = k + ((q < rem) ? q : rem - 1);
            const unsigned pa = sorted_f[idx];
            const int s = (pa >> 8) & 0x1FFFF;
            const uint2 d = fb2[(size_t)s * 16 + sl];
            const float2 c = wcl[pa >> 25];
            if (q < rem) {
                const float f0 = __uint_as_float(d.x << 16);
                const float f1 = __uint_as_float(d.x & 0xffff0000u);
                const float f2 = __uint_as_float(d.y << 16);
                const float f3 = __uint_as_float(d.y & 0xffff0000u);
                a0 = fmaf(c.x, f0, a0); a1 = fmaf(c.x, f1, a1);
                a2 = fmaf(c.x, f2, a2); a3 = fmaf(c.x, f3, a3);
                b0 = fmaf(c.y, f0, b0); b1 = fmaf(c.y, f1, b1);
                b2 = fmaf(c.y, f2, b2); b3 = fmaf(c.y, f3, b3);
            }
        }
        // reduce across the 4 quarters (lanes sl, sl+16, sl+32, sl+48)
        a0 += __shfl_xor(a0, 16); a0 += __shfl_xor(a0, 32);
        a1 += __shfl_xor(a1, 16); a1 += __shfl_xor(a1, 32);
        a2 += __shfl_xor(a2, 16); a2 += __shfl_xor(a2, 32);
        a3 += __shfl_xor(a3, 16); a3 += __shfl_xor(a3, 32);
        b0 += __shfl_xor(b0, 16); b0 += __shfl_xor(b0, 32);
        b1 += __shfl_xor(b1, 16); b1 += __shfl_xor(b1, 32);
        b2 += __shfl_xor(b2, 16); b2 += __shfl_xor(b2, 32);
        b3 += __shfl_xor(b3, 16); b3 += __shfl_xor(b3, 32);

        if (lane < 16) {
            Lin4[w][sl]      = make_float4(a0, a1, a2, a3);  // g0 cols 4sl..
            Lin4[w][16 + sl] = make_float4(b0, b1, b2, b3);  // g1
        }
        Lin[w * 192 + 128 + lane] = fv;                      // feat (f32)
    }
    __syncthreads();

    // ---- Phase 2: 24-row K-segment GEMM over 8 nodes ----
    #pragma unroll
    for (int j = 0; j < NODES_PER_GRP; ++j) {
        const float4* v4 = &Lin4[j][w * 6];
        float p0 = 0.f, p1 = 0.f;
        #pragma unroll
        for (int i4 = 0; i4 < 6; i4 += 2) {
            const float4 x = v4[i4];       // uniform -> LDS broadcast
            const float4 y = v4[i4 + 1];
            p0 = fmaf(x.x, wcol[4 * i4 + 0], p0);
            p0 = fmaf(x.y, wcol[4 * i4 + 1], p0);
            p0 = fmaf(x.z, wcol[4 * i4 + 2], p0);
            p0 = fmaf(x.w, wcol[4 * i4 + 3], p0);
            p1 = fmaf(y.x, wcol[4 * i4 + 4], p1);
            p1 = fmaf(y.y, wcol[4 * i4 + 5], p1);
            p1 = fmaf(y.z, wcol[4 * i4 + 6], p1);
            p1 = fmaf(y.w, wcol[4 * i4 + 7], p1);
        }
        ps[w][j][lane] = p0 + p1;
    }
    __syncthreads();

    // One output per thread: node slot = w, col = lane. Coalesced.
    float acc = bias;
    #pragma unroll
    for (int seg = 0; seg < 8; ++seg) acc += ps[seg][w][lane];
    out[(size_t)(grp * 8 + w) * 64 + lane] = acc;
}

// ---------------------------------------------------------------- launch
extern "C" void kernel_launch(void* const* d_in, const int* in_sizes, int n_in,
                              void* d_out, int out_size, void* d_ws, size_t ws_size,
                              hipStream_t stream) {
    const float* feat        = (const float*)d_in[0];
    const float* weight      = (const float*)d_in[1];
    const float* w_comp      = (const float*)d_in[2];
    const float* loop_weight = (const float*)d_in[3];
    const float* h_bias      = (const float*)d_in[4];
    const int*   src         = (const int*)d_in[5];
    const int*   dst         = (const int*)d_in[6];
    const int*   etypes      = (const int*)d_in[7];
    float* out = (float*)d_out;

    // ws layout (4B units), ~26 MB total, no aliasing:
    unsigned* sorted_c = (unsigned*)d_ws;                     // 1.6M u32
    unsigned* sorted_f = sorted_c + N_EDGES;                  // 1.6M u32
    unsigned* fbf      = sorted_f + N_EDGES;                  // 3.2M u32 (bf16 feat)
    int*      offsets  = (int*)(fbf + N_NODES * 32);          // N+1
    int*      bcnt     = offsets + (N_NODES + 1);             // NB
    int*      bbase    = bcnt + NB;                           // NB+1
    int*      bcursor  = bbase + NB + 1;                      // NB

    k_cvt<<<2048, 256, 0, stream>>>(feat, fbf);
    hipMemsetAsync(bcnt, 0, NB * sizeof(int), stream);
    k_bhist<<<(N_EDGES + 2047) / 2048, 256, 0, stream>>>(dst, bcnt);
    k_bscan<<<1, 512, 0, stream>>>(bcnt, bbase, bcursor);
    k_bscatter<<<(N_EDGES + SC_CHUNK - 1) / SC_CHUNK, 256, 0, stream>>>(
        src, dst, etypes, bcursor, sorted_c);
    k_fine<<<NB, BN, 0, stream>>>(sorted_c, bbase, offsets, sorted_f);
    k_gather_post<<<N_GRP, 512, 0, stream>>>(offsets, sorted_f, w_comp, feat,
                                             fbf, weight, loop_weight, h_bias, out);
}

// Round 14
// 150.678 us; speedup vs baseline: 1.2947x; 1.2947x over previous
//
#include <hip/hip_runtime.h>

// RelGraphConv basis-decomposition forward, MI355X.
//
// Input-space reformulation:
//   g[d, b, :] = sum_{e: dst_e = d} w_comp[et_e, b] * feat[src_e, :]   (b = 0,1)
//   out[d]     = [g0 | g1 | feat](192) @ Wcat(192x64) + bias,
//                Wcat = [V0; V1; W_loop]
//
// Pipeline:
//   k_cvt (feat->bf16) ; k_cvtw (Wcat^T -> bf16, padded) ; memset -> k_bhist
//   -> k_bscan -> k_bscatter (coarse 391-bucket multisplit) -> k_fine
//   (per-bucket exact per-node CSR) -> k_gather_post:
//     phase 1 (8 waves x 2 nodes): r12-proven ushort gather -> LDS bf16
//     phase 2 (4 waves): 16x64x192 post-GEMM as 24 x mfma_f32_16x16x32_bf16
//
// MFMA fragment mapping (learn_hip m89-verified family):
//   A[i][k]: lane l holds A[l&15][(l>>4)*8 + j]   (row-major LDS, 1 b128 read)
//   B[k][n]: lane l holds B[(l>>4)*8 + j][l&15]   (from W^T rows, 1 b128 read)
//   D[i][n]: lane l, reg r -> row (l>>4)*4+r, col l&15

constexpr int N_NODES  = 100000;
constexpr int N_EDGES  = 1600000;
constexpr int IN_FEAT  = 64;
constexpr int OUT_FEAT = 64;

constexpr int BN = 256;                                // nodes per bucket
constexpr int NB = (N_NODES + BN - 1) / BN;            // 391 buckets
constexpr int SC_CHUNK = 4096;                         // edges per scatter block

constexpr int NPG = 16;                                // nodes per block
constexpr int N_GRP = N_NODES / NPG;                   // 6250 (exact)
constexpr int LROW = 200;                              // padded row (in bf16)

typedef __attribute__((ext_vector_type(8))) short bf16x8;
typedef __attribute__((ext_vector_type(4))) float f32x4;

// entry pack: dst_low(8) | src(17) | etype(6)
__device__ __forceinline__ unsigned pack_entry(int d, int s, int r) {
    return (unsigned)(d & (BN - 1)) | ((unsigned)s << 8) | ((unsigned)r << 25);
}

__device__ __forceinline__ unsigned bf16_rne(float f) {
    unsigned b = __float_as_uint(f);
    b += 0x7fffu + ((b >> 16) & 1u);
    return b >> 16;
}

// ---------------------------------------------------------------- f32->bf16
__global__ __launch_bounds__(256) void k_cvt(const float* __restrict__ feat,
                                             unsigned* __restrict__ fbf) {
    const int total = N_NODES * 16;    // float4 count
    const float4* __restrict__ f4 = (const float4*)feat;
    uint2* __restrict__ o2 = (uint2*)fbf;
    for (int i = blockIdx.x * 256 + threadIdx.x; i < total; i += gridDim.x * 256) {
        const float4 f = f4[i];
        uint2 o;
        o.x = bf16_rne(f.x) | (bf16_rne(f.y) << 16);
        o.y = bf16_rne(f.z) | (bf16_rne(f.w) << 16);
        o2[i] = o;
    }
}

// Wcat^T, bf16, padded to LROW: wtb[n*LROW + r] = bf16(Wcat[r][n]), 64 x LROW.
__global__ __launch_bounds__(512) void k_cvtw(const float* __restrict__ weight,
                                              const float* __restrict__ loop_weight,
                                              unsigned short* __restrict__ wtb) {
    const int idx = blockIdx.x * 512 + threadIdx.x;
    if (idx >= 64 * LROW) return;
    const int n = idx / LROW, r = idx % LROW;
    float v = 0.0f;
    if (r < 128)      v = weight[r * 64 + n];          // V0;V1 rows contiguous
    else if (r < 192) v = loop_weight[(r - 128) * 64 + n];
    wtb[idx] = (unsigned short)bf16_rne(v);
}

// ---------------------------------------------------------------- coarse hist
__global__ __launch_bounds__(256) void k_bhist(const int* __restrict__ dst,
                                               int* __restrict__ bcnt) {
    __shared__ int hist[NB];
    const int t = threadIdx.x;
    for (int i = t; i < NB; i += 256) hist[i] = 0;
    __syncthreads();
    const int cbase = blockIdx.x * 2048;
    #pragma unroll
    for (int k = 0; k < 8; ++k) {
        const int e = cbase + k * 256 + t;
        if (e < N_EDGES) atomicAdd(&hist[dst[e] >> 8], 1);
    }
    __syncthreads();
    for (int i = t; i < NB; i += 256)
        if (hist[i]) atomicAdd(&bcnt[i], hist[i]);
}

// ---------------------------------------------------------------- coarse scan
__global__ __launch_bounds__(512) void k_bscan(const int* __restrict__ bcnt,
                                               int* __restrict__ bbase,
                                               int* __restrict__ bcursor) {
    __shared__ int part[512];
    const int t = threadIdx.x;
    const int v = (t < NB) ? bcnt[t] : 0;
    part[t] = v;
    __syncthreads();
    for (int d = 1; d < 512; d <<= 1) {
        const int u = (t >= d) ? part[t - d] : 0;
        __syncthreads();
        part[t] += u;
        __syncthreads();
    }
    if (t < NB) {
        const int ex = part[t] - v;   // exclusive
        bbase[t] = ex;
        bcursor[t] = ex;
    }
    if (t == 0) bbase[NB] = N_EDGES;
}

// ---------------------------------------------------------------- multisplit
__global__ __launch_bounds__(256) void k_bscatter(const int* __restrict__ src,
                                                  const int* __restrict__ dst,
                                                  const int* __restrict__ et,
                                                  int* __restrict__ bcursor,
                                                  unsigned* __restrict__ sorted_c) {
    __shared__ int hist[NB], gb[NB], lcur[NB];
    const int t = threadIdx.x;
    const int cbase = blockIdx.x * SC_CHUNK;
    for (int i = t; i < NB; i += 256) { hist[i] = 0; lcur[i] = 0; }
    __syncthreads();
    #pragma unroll 1
    for (int k = 0; k < SC_CHUNK / 256; ++k) {
        const int e = cbase + k * 256 + t;
        if (e < N_EDGES) atomicAdd(&hist[dst[e] >> 8], 1);
    }
    __syncthreads();
    for (int i = t; i < NB; i += 256) {
        const int c = hist[i];
        gb[i] = c ? atomicAdd(&bcursor[i], c) : 0;
    }
    __syncthreads();
    #pragma unroll 1
    for (int k = 0; k < SC_CHUNK / 256; ++k) {
        const int e = cbase + k * 256 + t;
        if (e < N_EDGES) {
            const int d = dst[e];
            const int bkt = d >> 8;
            const int r = atomicAdd(&lcur[bkt], 1);
            sorted_c[gb[bkt] + r] = pack_entry(d, src[e], et[e]);
        }
    }
}

// ---------------------------------------------------------------- fine CSR
__global__ __launch_bounds__(256) void k_fine(const unsigned* __restrict__ sorted_c,
                                              const int* __restrict__ bbase,
                                              int* __restrict__ offsets,
                                              unsigned* __restrict__ sorted_f) {
    __shared__ int cnt[BN];
    __shared__ int part[BN];
    __shared__ int cur[BN];
    const int t = threadIdx.x;
    const int b = blockIdx.x;
    cnt[t] = 0;
    __syncthreads();
    const int base = bbase[b];
    const int end  = bbase[b + 1];
    for (int k = base + t; k < end; k += 256)
        atomicAdd(&cnt[sorted_c[k] & (BN - 1)], 1);
    __syncthreads();
    const int v = cnt[t];
    part[t] = v;
    __syncthreads();
    for (int d = 1; d < BN; d <<= 1) {
        const int u = (t >= d) ? part[t - d] : 0;
        __syncthreads();
        part[t] += u;
        __syncthreads();
    }
    const int node = b * BN + t;
    const int off = base + part[t] - v;   // exclusive within bucket
    if (node < N_NODES) offsets[node] = off;
    cur[t] = off;
    if (b == NB - 1 && t == 0) offsets[N_NODES] = N_EDGES;
    __syncthreads();
    for (int k = base + t; k < end; k += 256) {
        const unsigned en = sorted_c[k];
        const int pos = atomicAdd(&cur[en & (BN - 1)], 1);
        sorted_f[pos] = en;
    }
}

// ---------------------------------------------------------------- fused
// 512 threads = 8 waves; 6250 blocks, 16 nodes each.
// Phase 1: wave w gathers nodes 2w, 2w+1 (sequential, r12-proven loop),
//          writes [g0|g1|feat] as bf16 into LinS row (LROW-padded).
// Phase 2: waves 0-3: wave w = N-tile w. 6 K-steps of
//          mfma_f32_16x16x32_bf16, A from LinS, B from WtS; direct store.
__global__ __launch_bounds__(512, 4) void k_gather_post(
    const int*      __restrict__ offsets,
    const unsigned* __restrict__ sorted_f,
    const float*    __restrict__ w_comp,      // (64, 2)
    const unsigned short* __restrict__ fbs,   // (N, 64) bf16
    const unsigned short* __restrict__ wtb,   // (64, LROW) bf16 = Wcat^T padded
    const float*    __restrict__ h_bias,      // (64,)
    float*          __restrict__ out)         // (N, 64)
{
    __shared__ unsigned short WtS[64 * LROW];   // 25.6 KB
    __shared__ unsigned short LinS[NPG * LROW]; // 6.4 KB
    __shared__ float2 wcl[64];

    const int tid  = threadIdx.x;
    const int lane = tid & 63;
    const int w    = tid >> 6;

    // stage W^T (bf16, already padded) and w_comp
    {
        const unsigned* __restrict__ wsrc = (const unsigned*)wtb;
        unsigned* __restrict__ wdst = (unsigned*)WtS;
        for (int i = tid; i < 64 * LROW / 2; i += 512) wdst[i] = wsrc[i];
        if (tid < 64) wcl[tid] = ((const float2*)w_comp)[tid];
    }
    __syncthreads();

    const int grp = blockIdx.x;

    // ---- Phase 1: two nodes per wave (r12-verbatim loop, bf16 out) ----
    #pragma unroll 1
    for (int half = 0; half < 2; ++half) {
        const int slot = 2 * w + half;
        const int n = __builtin_amdgcn_readfirstlane(grp * NPG + slot);
        const int start = __builtin_amdgcn_readfirstlane(offsets[n]);
        const int end   = __builtin_amdgcn_readfirstlane(offsets[n + 1]);

        float a0 = 0.f, b0 = 0.f, a1 = 0.f, b1 = 0.f;
        int k = start;
        for (; k + 7 < end; k += 8) {
            unsigned p[8]; float f[8];
            #pragma unroll
            for (int i = 0; i < 8; ++i) p[i] = sorted_f[k + i];   // uniform -> s_load
            #pragma unroll
            for (int i = 0; i < 8; ++i)
                f[i] = __uint_as_float(
                    (unsigned)fbs[(size_t)((p[i] >> 8) & 0x1FFFF) * 64 + lane] << 16);
            #pragma unroll
            for (int i = 0; i < 8; ++i) {
                const float2 c = wcl[p[i] >> 25];
                if (i & 1) { a1 = fmaf(c.x, f[i], a1); b1 = fmaf(c.y, f[i], b1); }
                else       { a0 = fmaf(c.x, f[i], a0); b0 = fmaf(c.y, f[i], b0); }
            }
        }
        for (; k + 3 < end; k += 4) {
            unsigned p[4]; float f[4];
            #pragma unroll
            for (int i = 0; i < 4; ++i) p[i] = sorted_f[k + i];
            #pragma unroll
            for (int i = 0; i < 4; ++i)
                f[i] = __uint_as_float(
                    (unsigned)fbs[(size_t)((p[i] >> 8) & 0x1FFFF) * 64 + lane] << 16);
            #pragma unroll
            for (int i = 0; i < 4; ++i) {
                const float2 c = wcl[p[i] >> 25];
                if (i & 1) { a1 = fmaf(c.x, f[i], a1); b1 = fmaf(c.y, f[i], b1); }
                else       { a0 = fmaf(c.x, f[i], a0); b0 = fmaf(c.y, f[i], b0); }
            }
        }
        for (; k < end; ++k) {
            const unsigned p0 = sorted_f[k];
            const float f0 = __uint_as_float(
                (unsigned)fbs[(size_t)((p0 >> 8) & 0x1FFFF) * 64 + lane] << 16);
            const float2 c0 = wcl[p0 >> 25];
            a0 = fmaf(c0.x, f0, a0); b0 = fmaf(c0.y, f0, b0);
        }
        LinS[slot * LROW + lane]       = (unsigned short)bf16_rne(a0 + a1);
        LinS[slot * LROW + 64 + lane]  = (unsigned short)bf16_rne(b0 + b1);
        LinS[slot * LROW + 128 + lane] = fbs[(size_t)n * 64 + lane];  // feat bf16
    }
    __syncthreads();

    // ---- Phase 2: 16x64x192 via MFMA; wave w (<4) = N-tile w ----
    if (w < 4) {
        const int r16 = lane & 15;     // A row / B col / D col (within tile)
        const int q   = lane >> 4;     // K-quarter / D row-quarter
        const float bv = h_bias[w * 16 + r16];
        f32x4 acc = {bv, bv, bv, bv};
        #pragma unroll
        for (int kt = 0; kt < 6; ++kt) {
            const bf16x8 a = *(const bf16x8*)&LinS[r16 * LROW + kt * 32 + q * 8];
            const bf16x8 b = *(const bf16x8*)&WtS[(w * 16 + r16) * LROW + kt * 32 + q * 8];
            acc = __builtin_amdgcn_mfma_f32_16x16x32_bf16(a, b, acc, 0, 0, 0);
        }
        #pragma unroll
        for (int r = 0; r < 4; ++r)
            out[(size_t)(grp * NPG + q * 4 + r) * 64 + w * 16 + r16] = acc[r];
    }
}

// ---------------------------------------------------------------- launch
extern "C" void kernel_launch(void* const* d_in, const int* in_sizes, int n_in,
                              void* d_out, int out_size, void* d_ws, size_t ws_size,
                              hipStream_t stream) {
    const float* feat        = (const float*)d_in[0];
    const float* weight      = (const float*)d_in[1];
    const float* w_comp      = (const float*)d_in[2];
    const float* loop_weight = (const float*)d_in[3];
    const float* h_bias      = (const float*)d_in[4];
    const int*   src         = (const int*)d_in[5];
    const int*   dst         = (const int*)d_in[6];
    const int*   etypes      = (const int*)d_in[7];
    float* out = (float*)d_out;

    // ws layout (4B units), ~26 MB total, no aliasing:
    unsigned* sorted_c = (unsigned*)d_ws;                     // 1.6M u32
    unsigned* sorted_f = sorted_c + N_EDGES;                  // 1.6M u32
    unsigned* fbf      = sorted_f + N_EDGES;                  // 3.2M u32 (bf16 feat)
    unsigned* wtbu     = fbf + N_NODES * 32;                  // 6400 u32 (bf16 Wcat^T)
    int*      offsets  = (int*)(wtbu + 64 * LROW / 2);        // N+1
    int*      bcnt     = offsets + (N_NODES + 1);             // NB
    int*      bbase    = bcnt + NB;                           // NB+1
    int*      bcursor  = bbase + NB + 1;                      // NB

    k_cvt<<<2048, 256, 0, stream>>>(feat, fbf);
    k_cvtw<<<(64 * LROW + 511) / 512, 512, 0, stream>>>(weight, loop_weight,
                                                        (unsigned short*)wtbu);
    hipMemsetAsync(bcnt, 0, NB * sizeof(int), stream);
    k_bhist<<<(N_EDGES + 2047) / 2048, 256, 0, stream>>>(dst, bcnt);
    k_bscan<<<1, 512, 0, stream>>>(bcnt, bbase, bcursor);
    k_bscatter<<<(N_EDGES + SC_CHUNK - 1) / SC_CHUNK, 256, 0, stream>>>(
        src, dst, etypes, bcursor, sorted_c);
    k_fine<<<NB, BN, 0, stream>>>(sorted_c, bbase, offsets, sorted_f);
    k_gather_post<<<N_GRP, 512, 0, stream>>>(offsets, sorted_f, w_comp,
                                             (const unsigned short*)fbf,
                                             (const unsigned short*)wtbu,
                                             h_bias, out);
}

// Round 15
// 125.972 us; speedup vs baseline: 1.5486x; 1.1961x over previous
//
#include <hip/hip_runtime.h>

// RelGraphConv basis-decomposition forward, MI355X.
//
// Input-space reformulation:
//   g[d, b, :] = sum_{e: dst_e = d} w_comp[et_e, b] * feat[src_e, :]   (b = 0,1)
//   out[d]     = [g0 | g1 | feat](192) @ Wcat(192x64) + bias,
//                Wcat = [V0; V1; W_loop]
//
// Pipeline (4 dispatches):
//   k_prep     : feat->bf16  ||  Wcat^T->bf16  ||  bcursor[b] = b*CAP
//   k_bscatter : coarse 391-bucket multisplit into FIXED-CAPACITY (CAP=4608
//                = mean 4096 + 8 sigma) padded buckets -- no hist/scan needed
//   k_fine     : per-bucket exact per-node CSR (LDS hist+scan), writes
//                offs[n]/ends[n] (padded positions) + reordered sorted_f
//   k_gather_post: phase 1 (8 waves x 2 nodes, 16-deep batches) gather ->
//                LDS bf16; phase 2: 16x64x192 GEMM as 24 x mfma 16x16x32.
//
// MFMA fragment mapping (learn_hip m89-verified family):
//   A[i][k]: lane l holds A[l&15][(l>>4)*8 + j]   (row-major LDS, 1 b128 read)
//   B[k][n]: lane l holds B[(l>>4)*8 + j][l&15]   (from W^T rows, 1 b128 read)
//   D[i][n]: lane l, reg r -> row (l>>4)*4+r, col l&15

constexpr int N_NODES  = 100000;
constexpr int N_EDGES  = 1600000;
constexpr int IN_FEAT  = 64;
constexpr int OUT_FEAT = 64;

constexpr int BN  = 256;                               // nodes per bucket
constexpr int NB  = (N_NODES + BN - 1) / BN;           // 391 buckets
constexpr int CAP = 4608;                              // bucket capacity (+8 sigma)
constexpr int SC_CHUNK = 4096;                         // edges per scatter block

constexpr int NPG = 16;                                // nodes per gather block
constexpr int N_GRP = N_NODES / NPG;                   // 6250 (exact)
constexpr int LROW = 200;                              // padded LDS row (bf16)

typedef __attribute__((ext_vector_type(8))) short bf16x8;
typedef __attribute__((ext_vector_type(4))) float f32x4;

// entry pack: dst_low(8) | src(17) | etype(6)
__device__ __forceinline__ unsigned pack_entry(int d, int s, int r) {
    return (unsigned)(d & (BN - 1)) | ((unsigned)s << 8) | ((unsigned)r << 25);
}

__device__ __forceinline__ unsigned bf16_rne(float f) {
    unsigned b = __float_as_uint(f);
    b += 0x7fffu + ((b >> 16) & 1u);
    return b >> 16;
}

// ---------------------------------------------------------------- prep
// blocks 0..2047: feat->bf16 (grid-stride); 2048..2049: bcursor init;
// 2050..2099: Wcat^T -> bf16 padded (64 x LROW).
__global__ __launch_bounds__(256) void k_prep(const float* __restrict__ feat,
                                              unsigned* __restrict__ fbf,
                                              const float* __restrict__ weight,
                                              const float* __restrict__ loop_weight,
                                              unsigned short* __restrict__ wtb,
                                              int* __restrict__ bcursor) {
    const int b = blockIdx.x, t = threadIdx.x;
    if (b < 2048) {
        const int total = N_NODES * 16;    // float4 count
        const float4* __restrict__ f4 = (const float4*)feat;
        uint2* __restrict__ o2 = (uint2*)fbf;
        for (int i = b * 256 + t; i < total; i += 2048 * 256) {
            const float4 f = f4[i];
            uint2 o;
            o.x = bf16_rne(f.x) | (bf16_rne(f.y) << 16);
            o.y = bf16_rne(f.z) | (bf16_rne(f.w) << 16);
            o2[i] = o;
        }
    } else if (b < 2050) {
        const int i = (b - 2048) * 256 + t;
        if (i < NB) bcursor[i] = i * CAP;
    } else {
        const int idx = (b - 2050) * 256 + t;  // 50 blocks x 256 = 12800 = 64*LROW
        const int n = idx / LROW, r = idx % LROW;
        float v = 0.0f;
        if (r < 128)      v = weight[r * 64 + n];          // V0;V1 rows contiguous
        else if (r < 192) v = loop_weight[(r - 128) * 64 + n];
        wtb[idx] = (unsigned short)bf16_rne(v);
    }
}

// ---------------------------------------------------------------- multisplit
__global__ __launch_bounds__(256) void k_bscatter(const int* __restrict__ src,
                                                  const int* __restrict__ dst,
                                                  const int* __restrict__ et,
                                                  int* __restrict__ bcursor,
                                                  unsigned* __restrict__ sorted_c) {
    __shared__ int hist[NB], gb[NB], lcur[NB];
    const int t = threadIdx.x;
    const int cbase = blockIdx.x * SC_CHUNK;
    for (int i = t; i < NB; i += 256) { hist[i] = 0; lcur[i] = 0; }
    __syncthreads();
    #pragma unroll 1
    for (int k = 0; k < SC_CHUNK / 256; ++k) {
        const int e = cbase + k * 256 + t;
        if (e < N_EDGES) atomicAdd(&hist[dst[e] >> 8], 1);
    }
    __syncthreads();
    for (int i = t; i < NB; i += 256) {
        const int c = hist[i];
        gb[i] = c ? atomicAdd(&bcursor[i], c) : 0;
    }
    __syncthreads();
    #pragma unroll 1
    for (int k = 0; k < SC_CHUNK / 256; ++k) {
        const int e = cbase + k * 256 + t;
        if (e < N_EDGES) {
            const int d = dst[e];
            const int bkt = d >> 8;
            const int r = atomicAdd(&lcur[bkt], 1);
            sorted_c[gb[bkt] + r] = pack_entry(d, src[e], et[e]);
        }
    }
}

// ---------------------------------------------------------------- fine CSR
// base = b*CAP (static); end = bcursor[b] (final cursor after scatter).
__global__ __launch_bounds__(256) void k_fine(const unsigned* __restrict__ sorted_c,
                                              const int* __restrict__ bcursor,
                                              int* __restrict__ offs,
                                              int* __restrict__ ends,
                                              unsigned* __restrict__ sorted_f) {
    __shared__ int cnt[BN];
    __shared__ int part[BN];
    __shared__ int cur[BN];
    const int t = threadIdx.x;
    const int b = blockIdx.x;
    cnt[t] = 0;
    __syncthreads();
    const int base = b * CAP;
    const int end  = bcursor[b];
    for (int k = base + t; k < end; k += 256)
        atomicAdd(&cnt[sorted_c[k] & (BN - 1)], 1);
    __syncthreads();
    const int v = cnt[t];
    part[t] = v;
    __syncthreads();
    for (int d = 1; d < BN; d <<= 1) {
        const int u = (t >= d) ? part[t - d] : 0;
        __syncthreads();
        part[t] += u;
        __syncthreads();
    }
    const int node = b * BN + t;
    const int off = base + part[t] - v;   // exclusive within bucket (padded pos)
    if (node < N_NODES) { offs[node] = off; ends[node] = off + v; }
    cur[t] = off;
    __syncthreads();
    for (int k = base + t; k < end; k += 256) {
        const unsigned en = sorted_c[k];
        const int pos = atomicAdd(&cur[en & (BN - 1)], 1);
        sorted_f[pos] = en;
    }
}

// ---------------------------------------------------------------- fused
// 512 threads = 8 waves; 6250 blocks, 16 nodes each.
// Phase 1: wave w gathers nodes 2w, 2w+1 (16-deep batches; 16 bf16 row
//          loads in flight), writes [g0|g1|feat] bf16 into LinS row.
// Phase 2: waves 0-3: wave w = N-tile w; 6 K-steps of mfma 16x16x32 bf16.
__global__ __launch_bounds__(512, 4) void k_gather_post(
    const int*      __restrict__ offs,
    const int*      __restrict__ ends,
    const unsigned* __restrict__ sorted_f,
    const float*    __restrict__ w_comp,      // (64, 2)
    const unsigned short* __restrict__ fbs,   // (N, 64) bf16
    const unsigned short* __restrict__ wtb,   // (64, LROW) bf16 = Wcat^T padded
    const float*    __restrict__ h_bias,      // (64,)
    float*          __restrict__ out)         // (N, 64)
{
    __shared__ unsigned short WtS[64 * LROW];   // 25.6 KB
    __shared__ unsigned short LinS[NPG * LROW]; // 6.4 KB
    __shared__ float2 wcl[64];

    const int tid  = threadIdx.x;
    const int lane = tid & 63;
    const int w    = tid >> 6;

    // stage W^T (bf16, already padded) and w_comp
    {
        const unsigned* __restrict__ wsrc = (const unsigned*)wtb;
        unsigned* __restrict__ wdst = (unsigned*)WtS;
        for (int i = tid; i < 64 * LROW / 2; i += 512) wdst[i] = wsrc[i];
        if (tid < 64) wcl[tid] = ((const float2*)w_comp)[tid];
    }
    __syncthreads();

    const int grp = blockIdx.x;

    // ---- Phase 1: two nodes per wave ----
    #pragma unroll 1
    for (int half = 0; half < 2; ++half) {
        const int slot = 2 * w + half;
        const int n = __builtin_amdgcn_readfirstlane(grp * NPG + slot);
        const int start = __builtin_amdgcn_readfirstlane(offs[n]);
        const int end   = __builtin_amdgcn_readfirstlane(ends[n]);

        float a0 = 0.f, b0 = 0.f, a1 = 0.f, b1 = 0.f;
        int k = start;
        for (; k + 15 < end; k += 16) {
            unsigned p[16]; float f[16];
            #pragma unroll
            for (int i = 0; i < 16; ++i) p[i] = sorted_f[k + i];  // uniform -> s_load
            #pragma unroll
            for (int i = 0; i < 16; ++i)
                f[i] = __uint_as_float(
                    (unsigned)fbs[(size_t)((p[i] >> 8) & 0x1FFFF) * 64 + lane] << 16);
            #pragma unroll
            for (int i = 0; i < 16; ++i) {
                const float2 c = wcl[p[i] >> 25];
                if (i & 1) { a1 = fmaf(c.x, f[i], a1); b1 = fmaf(c.y, f[i], b1); }
                else       { a0 = fmaf(c.x, f[i], a0); b0 = fmaf(c.y, f[i], b0); }
            }
        }
        for (; k + 7 < end; k += 8) {
            unsigned p[8]; float f[8];
            #pragma unroll
            for (int i = 0; i < 8; ++i) p[i] = sorted_f[k + i];
            #pragma unroll
            for (int i = 0; i < 8; ++i)
                f[i] = __uint_as_float(
                    (unsigned)fbs[(size_t)((p[i] >> 8) & 0x1FFFF) * 64 + lane] << 16);
            #pragma unroll
            for (int i = 0; i < 8; ++i) {
                const float2 c = wcl[p[i] >> 25];
                if (i & 1) { a1 = fmaf(c.x, f[i], a1); b1 = fmaf(c.y, f[i], b1); }
                else       { a0 = fmaf(c.x, f[i], a0); b0 = fmaf(c.y, f[i], b0); }
            }
        }
        for (; k + 3 < end; k += 4) {
            unsigned p[4]; float f[4];
            #pragma unroll
            for (int i = 0; i < 4; ++i) p[i] = sorted_f[k + i];
            #pragma unroll
            for (int i = 0; i < 4; ++i)
                f[i] = __uint_as_float(
                    (unsigned)fbs[(size_t)((p[i] >> 8) & 0x1FFFF) * 64 + lane] << 16);
            #pragma unroll
            for (int i = 0; i < 4; ++i) {
                const float2 c = wcl[p[i] >> 25];
                if (i & 1) { a1 = fmaf(c.x, f[i], a1); b1 = fmaf(c.y, f[i], b1); }
                else       { a0 = fmaf(c.x, f[i], a0); b0 = fmaf(c.y, f[i], b0); }
            }
        }
        for (; k < end; ++k) {
            const unsigned p0 = sorted_f[k];
            const float f0 = __uint_as_float(
                (unsigned)fbs[(size_t)((p0 >> 8) & 0x1FFFF) * 64 + lane] << 16);
            const float2 c0 = wcl[p0 >> 25];
            a0 = fmaf(c0.x, f0, a0); b0 = fmaf(c0.y, f0, b0);
        }
        LinS[slot * LROW + lane]       = (unsigned short)bf16_rne(a0 + a1);
        LinS[slot * LROW + 64 + lane]  = (unsigned short)bf16_rne(b0 + b1);
        LinS[slot * LROW + 128 + lane] = fbs[(size_t)n * 64 + lane];  // feat bf16
    }
    __syncthreads();

    // ---- Phase 2: 16x64x192 via MFMA; wave w (<4) = N-tile w ----
    if (w < 4) {
        const int r16 = lane & 15;     // A row / B col / D col (within tile)
        const int q   = lane >> 4;     // K-quarter / D row-quarter
        const float bv = h_bias[w * 16 + r16];
        f32x4 acc = {bv, bv, bv, bv};
        #pragma unroll
        for (int kt = 0; kt < 6; ++kt) {
            const bf16x8 a = *(const bf16x8*)&LinS[r16 * LROW + kt * 32 + q * 8];
            const bf16x8 b = *(const bf16x8*)&WtS[(w * 16 + r16) * LROW + kt * 32 + q * 8];
            acc = __builtin_amdgcn_mfma_f32_16x16x32_bf16(a, b, acc, 0, 0, 0);
        }
        #pragma unroll
        for (int r = 0; r < 4; ++r)
            out[(size_t)(grp * NPG + q * 4 + r) * 64 + w * 16 + r16] = acc[r];
    }
}

// ---------------------------------------------------------------- launch
extern "C" void kernel_launch(void* const* d_in, const int* in_sizes, int n_in,
                              void* d_out, int out_size, void* d_ws, size_t ws_size,
                              hipStream_t stream) {
    const float* feat        = (const float*)d_in[0];
    const float* weight      = (const float*)d_in[1];
    const float* w_comp      = (const float*)d_in[2];
    const float* loop_weight = (const float*)d_in[3];
    const float* h_bias      = (const float*)d_in[4];
    const int*   src         = (const int*)d_in[5];
    const int*   dst         = (const int*)d_in[6];
    const int*   etypes      = (const int*)d_in[7];
    float* out = (float*)d_out;

    // ws layout (4B units), ~28 MB total, no aliasing:
    unsigned* sorted_c = (unsigned*)d_ws;                     // NB*CAP u32 (padded)
    unsigned* sorted_f = sorted_c + (size_t)NB * CAP;         // NB*CAP u32 (padded)
    unsigned* fbf      = sorted_f + (size_t)NB * CAP;         // 3.2M u32 (bf16 feat)
    unsigned* wtbu     = fbf + N_NODES * 32;                  // 6400 u32 (bf16 Wcat^T)
    int*      offs     = (int*)(wtbu + 64 * LROW / 2);        // N
    int*      ends     = offs + N_NODES;                      // N
    int*      bcursor  = ends + N_NODES;                      // NB

    k_prep<<<2100, 256, 0, stream>>>(feat, fbf, weight, loop_weight,
                                     (unsigned short*)wtbu, bcursor);
    k_bscatter<<<(N_EDGES + SC_CHUNK - 1) / SC_CHUNK, 256, 0, stream>>>(
        src, dst, etypes, bcursor, sorted_c);
    k_fine<<<NB, BN, 0, stream>>>(sorted_c, bcursor, offs, ends, sorted_f);
    k_gather_post<<<N_GRP, 512, 0, stream>>>(offs, ends, sorted_f, w_comp,
                                             (const unsigned short*)fbf,
                                             (const unsigned short*)wtbu,
                                             h_bias, out);
}

// Round 16
// 124.247 us; speedup vs baseline: 1.5701x; 1.0139x over previous
//
#include <hip/hip_runtime.h>

// RelGraphConv basis-decomposition forward, MI355X.
//
// Input-space reformulation:
//   g[d, b, :] = sum_{e: dst_e = d} w_comp[et_e, b] * feat[src_e, :]   (b = 0,1)
//   out[d]     = [g0 | g1 | feat](192) @ Wcat(192x64) + bias,
//                Wcat = [V0; V1; W_loop]
//
// Pipeline (4 dispatches):
//   k_prep     : feat->bf16  ||  Wcat^T->bf16  ||  bcursor[b] = b*CAP
//   k_bscatter : coarse 391-bucket multisplit into FIXED-CAPACITY (CAP=4608)
//                padded buckets -- no hist/scan kernels needed
//   k_fine     : per-bucket exact per-node CSR (LDS hist+scan, 512 thr)
//   k_gather_post: phase 1 (8 waves x 2 nodes, 8-deep batches -- r14-proven;
//                r15's 16-deep regressed 68->75us via VGPR/occupancy) ->
//                LDS bf16; phase 2: 16x64x192 GEMM as 24 x mfma 16x16x32.

constexpr int N_NODES  = 100000;
constexpr int N_EDGES  = 1600000;
constexpr int IN_FEAT  = 64;
constexpr int OUT_FEAT = 64;

constexpr int BN  = 256;                               // nodes per bucket
constexpr int NB  = (N_NODES + BN - 1) / BN;           // 391 buckets
constexpr int CAP = 4608;                              // bucket capacity (+8 sigma)
constexpr int SC_CHUNK = 8192;                         // edges per scatter block

constexpr int NPG = 16;                                // nodes per gather block
constexpr int N_GRP = N_NODES / NPG;                   // 6250 (exact)
constexpr int LROW = 200;                              // padded LDS row (bf16)

typedef __attribute__((ext_vector_type(8))) short bf16x8;
typedef __attribute__((ext_vector_type(4))) float f32x4;

// entry pack: dst_low(8) | src(17) | etype(6)
__device__ __forceinline__ unsigned pack_entry(int d, int s, int r) {
    return (unsigned)(d & (BN - 1)) | ((unsigned)s << 8) | ((unsigned)r << 25);
}

__device__ __forceinline__ unsigned bf16_rne(float f) {
    unsigned b = __float_as_uint(f);
    b += 0x7fffu + ((b >> 16) & 1u);
    return b >> 16;
}

// ---------------------------------------------------------------- prep
// blocks 0..2047: feat->bf16 (grid-stride); 2048..2049: bcursor init;
// 2050..2099: Wcat^T -> bf16 padded (64 x LROW).
__global__ __launch_bounds__(256) void k_prep(const float* __restrict__ feat,
                                              unsigned* __restrict__ fbf,
                                              const float* __restrict__ weight,
                                              const float* __restrict__ loop_weight,
                                              unsigned short* __restrict__ wtb,
                                              int* __restrict__ bcursor) {
    const int b = blockIdx.x, t = threadIdx.x;
    if (b < 2048) {
        const int total = N_NODES * 16;    // float4 count
        const float4* __restrict__ f4 = (const float4*)feat;
        uint2* __restrict__ o2 = (uint2*)fbf;
        for (int i = b * 256 + t; i < total; i += 2048 * 256) {
            const float4 f = f4[i];
            uint2 o;
            o.x = bf16_rne(f.x) | (bf16_rne(f.y) << 16);
            o.y = bf16_rne(f.z) | (bf16_rne(f.w) << 16);
            o2[i] = o;
        }
    } else if (b < 2050) {
        const int i = (b - 2048) * 256 + t;
        if (i < NB) bcursor[i] = i * CAP;
    } else {
        const int idx = (b - 2050) * 256 + t;  // 50 blocks x 256 = 12800 = 64*LROW
        const int n = idx / LROW, r = idx % LROW;
        float v = 0.0f;
        if (r < 128)      v = weight[r * 64 + n];          // V0;V1 rows contiguous
        else if (r < 192) v = loop_weight[(r - 128) * 64 + n];
        wtb[idx] = (unsigned short)bf16_rne(v);
    }
}

// ---------------------------------------------------------------- multisplit
__global__ __launch_bounds__(256) void k_bscatter(const int* __restrict__ src,
                                                  const int* __restrict__ dst,
                                                  const int* __restrict__ et,
                                                  int* __restrict__ bcursor,
                                                  unsigned* __restrict__ sorted_c) {
    __shared__ int hist[NB], gb[NB], lcur[NB];
    const int t = threadIdx.x;
    const int cbase = blockIdx.x * SC_CHUNK;
    for (int i = t; i < NB; i += 256) { hist[i] = 0; lcur[i] = 0; }
    __syncthreads();
    #pragma unroll 1
    for (int k = 0; k < SC_CHUNK / 256; ++k) {
        const int e = cbase + k * 256 + t;
        if (e < N_EDGES) atomicAdd(&hist[dst[e] >> 8], 1);
    }
    __syncthreads();
    for (int i = t; i < NB; i += 256) {
        const int c = hist[i];
        gb[i] = c ? atomicAdd(&bcursor[i], c) : 0;
    }
    __syncthreads();
    #pragma unroll 1
    for (int k = 0; k < SC_CHUNK / 256; ++k) {
        const int e = cbase + k * 256 + t;
        if (e < N_EDGES) {
            const int d = dst[e];
            const int bkt = d >> 8;
            const int r = atomicAdd(&lcur[bkt], 1);
            sorted_c[gb[bkt] + r] = pack_entry(d, src[e], et[e]);
        }
    }
}

// ---------------------------------------------------------------- fine CSR
// base = b*CAP (static); end = bcursor[b] (final cursor after scatter).
// 512 threads: halves hist/reorder iteration counts; scan on t<256.
__global__ __launch_bounds__(512) void k_fine(const unsigned* __restrict__ sorted_c,
                                              const int* __restrict__ bcursor,
                                              int* __restrict__ offs,
                                              int* __restrict__ ends,
                                              unsigned* __restrict__ sorted_f) {
    __shared__ int cnt[BN];
    __shared__ int part[BN];
    __shared__ int cur[BN];
    const int t = threadIdx.x;
    const int b = blockIdx.x;
    if (t < BN) cnt[t] = 0;
    __syncthreads();
    const int base = b * CAP;
    const int end  = bcursor[b];
    for (int k = base + t; k < end; k += 512)
        atomicAdd(&cnt[sorted_c[k] & (BN - 1)], 1);
    __syncthreads();
    int v = 0;
    if (t < BN) {
        v = cnt[t];
        part[t] = v;
    }
    __syncthreads();
    for (int d = 1; d < BN; d <<= 1) {
        const int u = (t < BN && t >= d) ? part[t - d] : 0;
        __syncthreads();
        if (t < BN) part[t] += u;
        __syncthreads();
    }
    if (t < BN) {
        const int node = b * BN + t;
        const int off = base + part[t] - v;   // exclusive within bucket (padded)
        if (node < N_NODES) { offs[node] = off; ends[node] = off + v; }
        cur[t] = off;
    }
    __syncthreads();
    for (int k = base + t; k < end; k += 512) {
        const unsigned en = sorted_c[k];
        const int pos = atomicAdd(&cur[en & (BN - 1)], 1);
        sorted_f[pos] = en;
    }
}

// ---------------------------------------------------------------- fused
// 512 threads = 8 waves; 6250 blocks, 16 nodes each.
// Phase 1: wave w gathers nodes 2w, 2w+1 (8-deep batches, r14-proven),
//          writes [g0|g1|feat] bf16 into LinS row (LROW-padded).
// Phase 2: waves 0-3: wave w = N-tile w; 6 K-steps of mfma 16x16x32 bf16.
__global__ __launch_bounds__(512, 4) void k_gather_post(
    const int*      __restrict__ offs,
    const int*      __restrict__ ends,
    const unsigned* __restrict__ sorted_f,
    const float*    __restrict__ w_comp,      // (64, 2)
    const unsigned short* __restrict__ fbs,   // (N, 64) bf16
    const unsigned short* __restrict__ wtb,   // (64, LROW) bf16 = Wcat^T padded
    const float*    __restrict__ h_bias,      // (64,)
    float*          __restrict__ out)         // (N, 64)
{
    __shared__ unsigned short WtS[64 * LROW];   // 25.6 KB
    __shared__ unsigned short LinS[NPG * LROW]; // 6.4 KB
    __shared__ float2 wcl[64];

    const int tid  = threadIdx.x;
    const int lane = tid & 63;
    const int w    = tid >> 6;

    // stage W^T (bf16, already padded) and w_comp
    {
        const unsigned* __restrict__ wsrc = (const unsigned*)wtb;
        unsigned* __restrict__ wdst = (unsigned*)WtS;
        for (int i = tid; i < 64 * LROW / 2; i += 512) wdst[i] = wsrc[i];
        if (tid < 64) wcl[tid] = ((const float2*)w_comp)[tid];
    }
    __syncthreads();

    const int grp = blockIdx.x;

    // ---- Phase 1: two nodes per wave (8-deep batches) ----
    #pragma unroll 1
    for (int half = 0; half < 2; ++half) {
        const int slot = 2 * w + half;
        const int n = __builtin_amdgcn_readfirstlane(grp * NPG + slot);
        const int start = __builtin_amdgcn_readfirstlane(offs[n]);
        const int end   = __builtin_amdgcn_readfirstlane(ends[n]);

        float a0 = 0.f, b0 = 0.f, a1 = 0.f, b1 = 0.f;
        int k = start;
        for (; k + 7 < end; k += 8) {
            unsigned p[8]; float f[8];
            #pragma unroll
            for (int i = 0; i < 8; ++i) p[i] = sorted_f[k + i];   // uniform -> s_load
            #pragma unroll
            for (int i = 0; i < 8; ++i)
                f[i] = __uint_as_float(
                    (unsigned)fbs[(size_t)((p[i] >> 8) & 0x1FFFF) * 64 + lane] << 16);
            #pragma unroll
            for (int i = 0; i < 8; ++i) {
                const float2 c = wcl[p[i] >> 25];
                if (i & 1) { a1 = fmaf(c.x, f[i], a1); b1 = fmaf(c.y, f[i], b1); }
                else       { a0 = fmaf(c.x, f[i], a0); b0 = fmaf(c.y, f[i], b0); }
            }
        }
        for (; k + 3 < end; k += 4) {
            unsigned p[4]; float f[4];
            #pragma unroll
            for (int i = 0; i < 4; ++i) p[i] = sorted_f[k + i];
            #pragma unroll
            for (int i = 0; i < 4; ++i)
                f[i] = __uint_as_float(
                    (unsigned)fbs[(size_t)((p[i] >> 8) & 0x1FFFF) * 64 + lane] << 16);
            #pragma unroll
            for (int i = 0; i < 4; ++i) {
                const float2 c = wcl[p[i] >> 25];
                if (i & 1) { a1 = fmaf(c.x, f[i], a1); b1 = fmaf(c.y, f[i], b1); }
                else       { a0 = fmaf(c.x, f[i], a0); b0 = fmaf(c.y, f[i], b0); }
            }
        }
        for (; k < end; ++k) {
            const unsigned p0 = sorted_f[k];
            const float f0 = __uint_as_float(
                (unsigned)fbs[(size_t)((p0 >> 8) & 0x1FFFF) * 64 + lane] << 16);
            const float2 c0 = wcl[p0 >> 25];
            a0 = fmaf(c0.x, f0, a0); b0 = fmaf(c0.y, f0, b0);
        }
        LinS[slot * LROW + lane]       = (unsigned short)bf16_rne(a0 + a1);
        LinS[slot * LROW + 64 + lane]  = (unsigned short)bf16_rne(b0 + b1);
        LinS[slot * LROW + 128 + lane] = fbs[(size_t)n * 64 + lane];  // feat bf16
    }
    __syncthreads();

    // ---- Phase 2: 16x64x192 via MFMA; wave w (<4) = N-tile w ----
    if (w < 4) {
        const int r16 = lane & 15;     // A row / B col / D col (within tile)
        const int q   = lane >> 4;     // K-quarter / D row-quarter
        const float bv = h_bias[w * 16 + r16];
        f32x4 acc = {bv, bv, bv, bv};
        #pragma unroll
        for (int kt = 0; kt < 6; ++kt) {
            const bf16x8 a = *(const bf16x8*)&LinS[r16 * LROW + kt * 32 + q * 8];
            const bf16x8 b = *(const bf16x8*)&WtS[(w * 16 + r16) * LROW + kt * 32 + q * 8];
            acc = __builtin_amdgcn_mfma_f32_16x16x32_bf16(a, b, acc, 0, 0, 0);
        }
        #pragma unroll
        for (int r = 0; r < 4; ++r)
            out[(size_t)(grp * NPG + q * 4 + r) * 64 + w * 16 + r16] = acc[r];
    }
}

// ---------------------------------------------------------------- launch
extern "C" void kernel_launch(void* const* d_in, const int* in_sizes, int n_in,
                              void* d_out, int out_size, void* d_ws, size_t ws_size,
                              hipStream_t stream) {
    const float* feat        = (const float*)d_in[0];
    const float* weight      = (const float*)d_in[1];
    const float* w_comp      = (const float*)d_in[2];
    const float* loop_weight = (const float*)d_in[3];
    const float* h_bias      = (const float*)d_in[4];
    const int*   src         = (const int*)d_in[5];
    const int*   dst         = (const int*)d_in[6];
    const int*   etypes      = (const int*)d_in[7];
    float* out = (float*)d_out;

    // ws layout (4B units), ~28 MB total, no aliasing:
    unsigned* sorted_c = (unsigned*)d_ws;                     // NB*CAP u32 (padded)
    unsigned* sorted_f = sorted_c + (size_t)NB * CAP;         // NB*CAP u32 (padded)
    unsigned* fbf      = sorted_f + (size_t)NB * CAP;         // 3.2M u32 (bf16 feat)
    unsigned* wtbu     = fbf + N_NODES * 32;                  // 6400 u32 (bf16 Wcat^T)
    int*      offs     = (int*)(wtbu + 64 * LROW / 2);        // N
    int*      ends     = offs + N_NODES;                      // N
    int*      bcursor  = ends + N_NODES;                      // NB

    k_prep<<<2100, 256, 0, stream>>>(feat, fbf, weight, loop_weight,
                                     (unsigned short*)wtbu, bcursor);
    k_bscatter<<<(N_EDGES + SC_CHUNK - 1) / SC_CHUNK, 256, 0, stream>>>(
        src, dst, etypes, bcursor, sorted_c);
    k_fine<<<NB, 512, 0, stream>>>(sorted_c, bcursor, offs, ends, sorted_f);
    k_gather_post<<<N_GRP, 512, 0, stream>>>(offs, ends, sorted_f, w_comp,
                                             (const unsigned short*)fbf,
                                             (const unsigned short*)wtbu,
                                             h_bias, out);
}

// Round 17
// 121.828 us; speedup vs baseline: 1.6013x; 1.0199x over previous
//
#include <hip/hip_runtime.h>

// RelGraphConv basis-decomposition forward, MI355X.
//
// Input-space reformulation:
//   g[d, b, :] = sum_{e: dst_e = d} w_comp[et_e, b] * feat[src_e, :]   (b = 0,1)
//   out[d]     = [g0 | g1 | feat](192) @ Wcat(192x64) + bias,
//                Wcat = [V0; V1; W_loop]
//
// Pipeline (3 dispatches + memset):
//   memset(bcnt)  : per-bucket counts start at 0
//   k_scatter_prep: blocks 0..195 = coarse 391-bucket multisplit into
//                   fixed-capacity buckets (pos = b*CAP + atomic count);
//                   blocks 196..1219 = feat->bf16; 1220..1269 = Wcat^T->bf16
//   k_fine        : per-bucket exact per-node CSR (LDS hist+scan, 512 thr)
//   k_gather_post : phase 1 = 8 waves x 2 nodes INTERLEAVED (A/B batches,
//                   16 loads in flight, 8-deep chains — inner body is the
//                   r14-proven code); phase 2 = 16x64x192 GEMM via 24 x
//                   mfma_f32_16x16x32_bf16.

constexpr int N_NODES  = 100000;
constexpr int N_EDGES  = 1600000;
constexpr int IN_FEAT  = 64;
constexpr int OUT_FEAT = 64;

constexpr int BN  = 256;                               // nodes per bucket
constexpr int NB  = (N_NODES + BN - 1) / BN;           // 391 buckets
constexpr int CAP = 4608;                              // bucket capacity (+8 sigma)
constexpr int SC_CHUNK = 8192;                         // edges per scatter block
constexpr int NCH = (N_EDGES + SC_CHUNK - 1) / SC_CHUNK;  // 196 scatter blocks
constexpr int CVT_BLOCKS = 1024;                       // feat cvt blocks
constexpr int W_BLOCKS = 50;                           // 64*LROW/256 wtb blocks

constexpr int NPG = 16;                                // nodes per gather block
constexpr int N_GRP = N_NODES / NPG;                   // 6250 (exact)
constexpr int LROW = 200;                              // padded LDS row (bf16)

typedef __attribute__((ext_vector_type(8))) short bf16x8;
typedef __attribute__((ext_vector_type(4))) float f32x4;

// entry pack: dst_low(8) | src(17) | etype(6)
__device__ __forceinline__ unsigned pack_entry(int d, int s, int r) {
    return (unsigned)(d & (BN - 1)) | ((unsigned)s << 8) | ((unsigned)r << 25);
}

__device__ __forceinline__ unsigned bf16_rne(float f) {
    unsigned b = __float_as_uint(f);
    b += 0x7fffu + ((b >> 16) & 1u);
    return b >> 16;
}

// ------------------------------------------------- fused scatter + convert
__global__ __launch_bounds__(256) void k_scatter_prep(
    const int* __restrict__ src, const int* __restrict__ dst,
    const int* __restrict__ et,  int* __restrict__ bcnt,
    unsigned* __restrict__ sorted_c,
    const float* __restrict__ feat, unsigned* __restrict__ fbf,
    const float* __restrict__ weight, const float* __restrict__ loop_weight,
    unsigned short* __restrict__ wtb)
{
    __shared__ int hist[NB], gb[NB], lcur[NB];
    const int b = blockIdx.x, t = threadIdx.x;

    if (b < NCH) {  // ---- multisplit scatter chunk ----
        const int cbase = b * SC_CHUNK;
        for (int i = t; i < NB; i += 256) { hist[i] = 0; lcur[i] = 0; }
        __syncthreads();
        #pragma unroll 1
        for (int k = 0; k < SC_CHUNK / 256; ++k) {
            const int e = cbase + k * 256 + t;
            if (e < N_EDGES) atomicAdd(&hist[dst[e] >> 8], 1);
        }
        __syncthreads();
        for (int i = t; i < NB; i += 256) {
            const int c = hist[i];
            gb[i] = c ? (i * CAP + atomicAdd(&bcnt[i], c)) : 0;
        }
        __syncthreads();
        #pragma unroll 1
        for (int k = 0; k < SC_CHUNK / 256; ++k) {
            const int e = cbase + k * 256 + t;
            if (e < N_EDGES) {
                const int d = dst[e];
                const int bkt = d >> 8;
                const int r = atomicAdd(&lcur[bkt], 1);
                sorted_c[gb[bkt] + r] = pack_entry(d, src[e], et[e]);
            }
        }
    } else if (b < NCH + CVT_BLOCKS) {  // ---- feat -> bf16 ----
        const int bb = b - NCH;
        const int total = N_NODES * 16;    // float4 count
        const float4* __restrict__ f4 = (const float4*)feat;
        uint2* __restrict__ o2 = (uint2*)fbf;
        for (int i = bb * 256 + t; i < total; i += CVT_BLOCKS * 256) {
            const float4 f = f4[i];
            uint2 o;
            o.x = bf16_rne(f.x) | (bf16_rne(f.y) << 16);
            o.y = bf16_rne(f.z) | (bf16_rne(f.w) << 16);
            o2[i] = o;
        }
    } else {  // ---- Wcat^T -> bf16 padded (64 x LROW) ----
        const int idx = (b - NCH - CVT_BLOCKS) * 256 + t;
        const int n = idx / LROW, r = idx % LROW;
        float v = 0.0f;
        if (r < 128)      v = weight[r * 64 + n];          // V0;V1 rows contiguous
        else if (r < 192) v = loop_weight[(r - 128) * 64 + n];
        wtb[idx] = (unsigned short)bf16_rne(v);
    }
}

// ---------------------------------------------------------------- fine CSR
// base = b*CAP; end = base + bcnt[b] (count written by scatter atomics).
__global__ __launch_bounds__(512) void k_fine(const unsigned* __restrict__ sorted_c,
                                              const int* __restrict__ bcnt,
                                              int* __restrict__ offs,
                                              int* __restrict__ ends,
                                              unsigned* __restrict__ sorted_f) {
    __shared__ int cnt[BN];
    __shared__ int part[BN];
    __shared__ int cur[BN];
    const int t = threadIdx.x;
    const int b = blockIdx.x;
    if (t < BN) cnt[t] = 0;
    __syncthreads();
    const int base = b * CAP;
    const int end  = base + bcnt[b];
    for (int k = base + t; k < end; k += 512)
        atomicAdd(&cnt[sorted_c[k] & (BN - 1)], 1);
    __syncthreads();
    int v = 0;
    if (t < BN) {
        v = cnt[t];
        part[t] = v;
    }
    __syncthreads();
    for (int d = 1; d < BN; d <<= 1) {
        const int u = (t < BN && t >= d) ? part[t - d] : 0;
        __syncthreads();
        if (t < BN) part[t] += u;
        __syncthreads();
    }
    if (t < BN) {
        const int node = b * BN + t;
        const int off = base + part[t] - v;   // exclusive within bucket (padded)
        if (node < N_NODES) { offs[node] = off; ends[node] = off + v; }
        cur[t] = off;
    }
    __syncthreads();
    for (int k = base + t; k < end; k += 512) {
        const unsigned en = sorted_c[k];
        const int pos = atomicAdd(&cur[en & (BN - 1)], 1);
        sorted_f[pos] = en;
    }
}

// ---------------------------------------------------------------- fused
// 512 threads = 8 waves; 6250 blocks, 16 nodes each.
// Phase 1: wave w gathers nodes 2w (A) and 2w+1 (B) INTERLEAVED: while both
//          have a full 8-batch, issue both entry sets + 16 feat loads, then
//          both FMA blocks (16 loads in flight, chains stay 8-deep). Tails
//          drain per node with the proven 8/4/1 ladder.
// Phase 2: waves 0-3: wave w = N-tile w; 6 K-steps of mfma 16x16x32 bf16.
__global__ __launch_bounds__(512, 4) void k_gather_post(
    const int*      __restrict__ offs,
    const int*      __restrict__ ends,
    const unsigned* __restrict__ sorted_f,
    const float*    __restrict__ w_comp,      // (64, 2)
    const unsigned short* __restrict__ fbs,   // (N, 64) bf16
    const unsigned short* __restrict__ wtb,   // (64, LROW) bf16 = Wcat^T padded
    const float*    __restrict__ h_bias,      // (64,)
    float*          __restrict__ out)         // (N, 64)
{
    __shared__ unsigned short WtS[64 * LROW];   // 25.6 KB
    __shared__ unsigned short LinS[NPG * LROW]; // 6.4 KB
    __shared__ float2 wcl[64];

    const int tid  = threadIdx.x;
    const int lane = tid & 63;
    const int w    = tid >> 6;

    // stage W^T (bf16, already padded) and w_comp
    {
        const unsigned* __restrict__ wsrc = (const unsigned*)wtb;
        unsigned* __restrict__ wdst = (unsigned*)WtS;
        for (int i = tid; i < 64 * LROW / 2; i += 512) wdst[i] = wsrc[i];
        if (tid < 64) wcl[tid] = ((const float2*)w_comp)[tid];
    }
    __syncthreads();

    const int grp = blockIdx.x;

    // ---- Phase 1: two nodes per wave, interleaved ----
    {
        const int nA = __builtin_amdgcn_readfirstlane(grp * NPG + 2 * w);
        const int nB = nA + 1;
        const int sA = __builtin_amdgcn_readfirstlane(offs[nA]);
        const int eA = __builtin_amdgcn_readfirstlane(ends[nA]);
        const int sB = __builtin_amdgcn_readfirstlane(offs[nB]);
        const int eB = __builtin_amdgcn_readfirstlane(ends[nB]);

        float aA0 = 0.f, bA0 = 0.f, aA1 = 0.f, bA1 = 0.f;
        float aB0 = 0.f, bB0 = 0.f, aB1 = 0.f, bB1 = 0.f;
        int kA = sA, kB = sB;

        // interleaved main loop: both nodes have a full 8-batch
        while (kA + 7 < eA && kB + 7 < eB) {
            unsigned pA[8], pB[8]; float fA[8], fB[8];
            #pragma unroll
            for (int i = 0; i < 8; ++i) pA[i] = sorted_f[kA + i];  // s_load
            #pragma unroll
            for (int i = 0; i < 8; ++i) pB[i] = sorted_f[kB + i];
            #pragma unroll
            for (int i = 0; i < 8; ++i)
                fA[i] = __uint_as_float(
                    (unsigned)fbs[(size_t)((pA[i] >> 8) & 0x1FFFF) * 64 + lane] << 16);
            #pragma unroll
            for (int i = 0; i < 8; ++i)
                fB[i] = __uint_as_float(
                    (unsigned)fbs[(size_t)((pB[i] >> 8) & 0x1FFFF) * 64 + lane] << 16);
            #pragma unroll
            for (int i = 0; i < 8; ++i) {
                const float2 c = wcl[pA[i] >> 25];
                if (i & 1) { aA1 = fmaf(c.x, fA[i], aA1); bA1 = fmaf(c.y, fA[i], bA1); }
                else       { aA0 = fmaf(c.x, fA[i], aA0); bA0 = fmaf(c.y, fA[i], bA0); }
            }
            #pragma unroll
            for (int i = 0; i < 8; ++i) {
                const float2 c = wcl[pB[i] >> 25];
                if (i & 1) { aB1 = fmaf(c.x, fB[i], aB1); bB1 = fmaf(c.y, fB[i], bB1); }
                else       { aB0 = fmaf(c.x, fB[i], aB0); bB0 = fmaf(c.y, fB[i], bB0); }
            }
            kA += 8; kB += 8;
        }

        // drain node A (proven 8/4/1 ladder)
        for (; kA + 7 < eA; kA += 8) {
            unsigned p[8]; float f[8];
            #pragma unroll
            for (int i = 0; i < 8; ++i) p[i] = sorted_f[kA + i];
            #pragma unroll
            for (int i = 0; i < 8; ++i)
                f[i] = __uint_as_float(
                    (unsigned)fbs[(size_t)((p[i] >> 8) & 0x1FFFF) * 64 + lane] << 16);
            #pragma unroll
            for (int i = 0; i < 8; ++i) {
                const float2 c = wcl[p[i] >> 25];
                if (i & 1) { aA1 = fmaf(c.x, f[i], aA1); bA1 = fmaf(c.y, f[i], bA1); }
                else       { aA0 = fmaf(c.x, f[i], aA0); bA0 = fmaf(c.y, f[i], bA0); }
            }
        }
        for (; kA + 3 < eA; kA += 4) {
            unsigned p[4]; float f[4];
            #pragma unroll
            for (int i = 0; i < 4; ++i) p[i] = sorted_f[kA + i];
            #pragma unroll
            for (int i = 0; i < 4; ++i)
                f[i] = __uint_as_float(
                    (unsigned)fbs[(size_t)((p[i] >> 8) & 0x1FFFF) * 64 + lane] << 16);
            #pragma unroll
            for (int i = 0; i < 4; ++i) {
                const float2 c = wcl[p[i] >> 25];
                if (i & 1) { aA1 = fmaf(c.x, f[i], aA1); bA1 = fmaf(c.y, f[i], bA1); }
                else       { aA0 = fmaf(c.x, f[i], aA0); bA0 = fmaf(c.y, f[i], bA0); }
            }
        }
        for (; kA < eA; ++kA) {
            const unsigned p0 = sorted_f[kA];
            const float f0 = __uint_as_float(
                (unsigned)fbs[(size_t)((p0 >> 8) & 0x1FFFF) * 64 + lane] << 16);
            const float2 c0 = wcl[p0 >> 25];
            aA0 = fmaf(c0.x, f0, aA0); bA0 = fmaf(c0.y, f0, bA0);
        }

        // drain node B
        for (; kB + 7 < eB; kB += 8) {
            unsigned p[8]; float f[8];
            #pragma unroll
            for (int i = 0; i < 8; ++i) p[i] = sorted_f[kB + i];
            #pragma unroll
            for (int i = 0; i < 8; ++i)
                f[i] = __uint_as_float(
                    (unsigned)fbs[(size_t)((p[i] >> 8) & 0x1FFFF) * 64 + lane] << 16);
            #pragma unroll
            for (int i = 0; i < 8; ++i) {
                const float2 c = wcl[p[i] >> 25];
                if (i & 1) { aB1 = fmaf(c.x, f[i], aB1); bB1 = fmaf(c.y, f[i], bB1); }
                else       { aB0 = fmaf(c.x, f[i], aB0); bB0 = fmaf(c.y, f[i], bB0); }
            }
        }
        for (; kB + 3 < eB; kB += 4) {
            unsigned p[4]; float f[4];
            #pragma unroll
            for (int i = 0; i < 4; ++i) p[i] = sorted_f[kB + i];
            #pragma unroll
            for (int i = 0; i < 4; ++i)
                f[i] = __uint_as_float(
                    (unsigned)fbs[(size_t)((p[i] >> 8) & 0x1FFFF) * 64 + lane] << 16);
            #pragma unroll
            for (int i = 0; i < 4; ++i) {
                const float2 c = wcl[p[i] >> 25];
                if (i & 1) { aB1 = fmaf(c.x, f[i], aB1); bB1 = fmaf(c.y, f[i], bB1); }
                else       { aB0 = fmaf(c.x, f[i], aB0); bB0 = fmaf(c.y, f[i], bB0); }
            }
        }
        for (; kB < eB; ++kB) {
            const unsigned p0 = sorted_f[kB];
            const float f0 = __uint_as_float(
                (unsigned)fbs[(size_t)((p0 >> 8) & 0x1FFFF) * 64 + lane] << 16);
            const float2 c0 = wcl[p0 >> 25];
            aB0 = fmaf(c0.x, f0, aB0); bB0 = fmaf(c0.y, f0, bB0);
        }

        const int slotA = 2 * w, slotB = 2 * w + 1;
        LinS[slotA * LROW + lane]       = (unsigned short)bf16_rne(aA0 + aA1);
        LinS[slotA * LROW + 64 + lane]  = (unsigned short)bf16_rne(bA0 + bA1);
        LinS[slotA * LROW + 128 + lane] = fbs[(size_t)nA * 64 + lane];
        LinS[slotB * LROW + lane]       = (unsigned short)bf16_rne(aB0 + aB1);
        LinS[slotB * LROW + 64 + lane]  = (unsigned short)bf16_rne(bB0 + bB1);
        LinS[slotB * LROW + 128 + lane] = fbs[(size_t)nB * 64 + lane];
    }
    __syncthreads();

    // ---- Phase 2: 16x64x192 via MFMA; wave w (<4) = N-tile w ----
    if (w < 4) {
        const int r16 = lane & 15;     // A row / B col / D col (within tile)
        const int q   = lane >> 4;     // K-quarter / D row-quarter
        const float bv = h_bias[w * 16 + r16];
        f32x4 acc = {bv, bv, bv, bv};
        #pragma unroll
        for (int kt = 0; kt < 6; ++kt) {
            const bf16x8 a = *(const bf16x8*)&LinS[r16 * LROW + kt * 32 + q * 8];
            const bf16x8 b = *(const bf16x8*)&WtS[(w * 16 + r16) * LROW + kt * 32 + q * 8];
            acc = __builtin_amdgcn_mfma_f32_16x16x32_bf16(a, b, acc, 0, 0, 0);
        }
        #pragma unroll
        for (int r = 0; r < 4; ++r)
            out[(size_t)(grp * NPG + q * 4 + r) * 64 + w * 16 + r16] = acc[r];
    }
}

// ---------------------------------------------------------------- launch
extern "C" void kernel_launch(void* const* d_in, const int* in_sizes, int n_in,
                              void* d_out, int out_size, void* d_ws, size_t ws_size,
                              hipStream_t stream) {
    const float* feat        = (const float*)d_in[0];
    const float* weight      = (const float*)d_in[1];
    const float* w_comp      = (const float*)d_in[2];
    const float* loop_weight = (const float*)d_in[3];
    const float* h_bias      = (const float*)d_in[4];
    const int*   src         = (const int*)d_in[5];
    const int*   dst         = (const int*)d_in[6];
    const int*   etypes      = (const int*)d_in[7];
    float* out = (float*)d_out;

    // ws layout (4B units), ~28 MB total, no aliasing:
    unsigned* sorted_c = (unsigned*)d_ws;                     // NB*CAP u32 (padded)
    unsigned* sorted_f = sorted_c + (size_t)NB * CAP;         // NB*CAP u32 (padded)
    unsigned* fbf      = sorted_f + (size_t)NB * CAP;         // 3.2M u32 (bf16 feat)
    unsigned* wtbu     = fbf + N_NODES * 32;                  // 6400 u32 (bf16 Wcat^T)
    int*      offs     = (int*)(wtbu + 64 * LROW / 2);        // N
    int*      ends     = offs + N_NODES;                      // N
    int*      bcnt     = ends + N_NODES;                      // NB

    hipMemsetAsync(bcnt, 0, NB * sizeof(int), stream);
    k_scatter_prep<<<NCH + CVT_BLOCKS + W_BLOCKS, 256, 0, stream>>>(
        src, dst, etypes, bcnt, sorted_c, feat, fbf, weight, loop_weight,
        (unsigned short*)wtbu);
    k_fine<<<NB, 512, 0, stream>>>(sorted_c, bcnt, offs, ends, sorted_f);
    k_gather_post<<<N_GRP, 512, 0, stream>>>(offs, ends, sorted_f, w_comp,
                                             (const unsigned short*)fbf,
                                             (const unsigned short*)wtbu,
                                             h_bias, out);
}

// Round 18
// 113.838 us; speedup vs baseline: 1.7137x; 1.0702x over previous
//
#include <hip/hip_runtime.h>

// RelGraphConv basis-decomposition forward, MI355X.
//
// Input-space reformulation:
//   g[d, b, :] = sum_{e: dst_e = d} w_comp[et_e, b] * feat[src_e, :]   (b = 0,1)
//   out[d]     = [g0 | g1 | feat](192) @ Wcat(192x64) + bias,
//                Wcat = [V0; V1; W_loop]
//
// Pipeline (3 dispatches + memset):
//   memset(bcnt)  : per-bucket counts start at 0
//   k_scatter_prep: 512 thr; blocks 0..195 = coarse 391-bucket multisplit
//                   into fixed-capacity buckets; then feat->bf16; Wcat^T->bf16
//   k_fine        : per-bucket exact per-node CSR (LDS hist+scan, 1024 thr)
//   k_gather_post : phase 1 = 8 waves x 2 nodes interleaved (r17-proven);
//                   phase 2 = 16x64x192 GEMM via 24 x mfma_f32_16x16x32_bf16
//                   with B-fragments in REGISTERS (no WtS staging; LDS 7 KB).

constexpr int N_NODES  = 100000;
constexpr int N_EDGES  = 1600000;
constexpr int IN_FEAT  = 64;
constexpr int OUT_FEAT = 64;

constexpr int BN  = 256;                               // nodes per bucket
constexpr int NB  = (N_NODES + BN - 1) / BN;           // 391 buckets
constexpr int CAP = 4608;                              // bucket capacity (+8 sigma)
constexpr int SC_CHUNK = 8192;                         // edges per scatter block
constexpr int NCH = (N_EDGES + SC_CHUNK - 1) / SC_CHUNK;  // 196 scatter blocks
constexpr int CVT_BLOCKS = 512;                        // feat cvt blocks (512 thr)
constexpr int W_BLOCKS = 25;                           // 64*LROW/512 wtb blocks

constexpr int NPG = 16;                                // nodes per gather block
constexpr int N_GRP = N_NODES / NPG;                   // 6250 (exact)
constexpr int LROW = 200;                              // padded row (bf16)

typedef __attribute__((ext_vector_type(8))) short bf16x8;
typedef __attribute__((ext_vector_type(4))) float f32x4;

// entry pack: dst_low(8) | src(17) | etype(6)
__device__ __forceinline__ unsigned pack_entry(int d, int s, int r) {
    return (unsigned)(d & (BN - 1)) | ((unsigned)s << 8) | ((unsigned)r << 25);
}

__device__ __forceinline__ unsigned bf16_rne(float f) {
    unsigned b = __float_as_uint(f);
    b += 0x7fffu + ((b >> 16) & 1u);
    return b >> 16;
}

// ------------------------------------------------- fused scatter + convert
__global__ __launch_bounds__(512) void k_scatter_prep(
    const int* __restrict__ src, const int* __restrict__ dst,
    const int* __restrict__ et,  int* __restrict__ bcnt,
    unsigned* __restrict__ sorted_c,
    const float* __restrict__ feat, unsigned* __restrict__ fbf,
    const float* __restrict__ weight, const float* __restrict__ loop_weight,
    unsigned short* __restrict__ wtb)
{
    __shared__ int hist[NB], gb[NB], lcur[NB];
    const int b = blockIdx.x, t = threadIdx.x;

    if (b < NCH) {  // ---- multisplit scatter chunk ----
        const int cbase = b * SC_CHUNK;
        for (int i = t; i < NB; i += 512) { hist[i] = 0; lcur[i] = 0; }
        __syncthreads();
        #pragma unroll 1
        for (int k = 0; k < SC_CHUNK / 512; ++k) {
            const int e = cbase + k * 512 + t;
            if (e < N_EDGES) atomicAdd(&hist[dst[e] >> 8], 1);
        }
        __syncthreads();
        for (int i = t; i < NB; i += 512) {
            const int c = hist[i];
            gb[i] = c ? (i * CAP + atomicAdd(&bcnt[i], c)) : 0;
        }
        __syncthreads();
        #pragma unroll 1
        for (int k = 0; k < SC_CHUNK / 512; ++k) {
            const int e = cbase + k * 512 + t;
            if (e < N_EDGES) {
                const int d = dst[e];
                const int bkt = d >> 8;
                const int r = atomicAdd(&lcur[bkt], 1);
                sorted_c[gb[bkt] + r] = pack_entry(d, src[e], et[e]);
            }
        }
    } else if (b < NCH + CVT_BLOCKS) {  // ---- feat -> bf16 ----
        const int bb = b - NCH;
        const int total = N_NODES * 16;    // float4 count
        const float4* __restrict__ f4 = (const float4*)feat;
        uint2* __restrict__ o2 = (uint2*)fbf;
        for (int i = bb * 512 + t; i < total; i += CVT_BLOCKS * 512) {
            const float4 f = f4[i];
            uint2 o;
            o.x = bf16_rne(f.x) | (bf16_rne(f.y) << 16);
            o.y = bf16_rne(f.z) | (bf16_rne(f.w) << 16);
            o2[i] = o;
        }
    } else {  // ---- Wcat^T -> bf16 padded (64 x LROW) ----
        const int idx = (b - NCH - CVT_BLOCKS) * 512 + t;  // 25*512 = 12800
        const int n = idx / LROW, r = idx % LROW;
        float v = 0.0f;
        if (r < 128)      v = weight[r * 64 + n];          // V0;V1 rows contiguous
        else if (r < 192) v = loop_weight[(r - 128) * 64 + n];
        wtb[idx] = (unsigned short)bf16_rne(v);
    }
}

// ---------------------------------------------------------------- fine CSR
// base = b*CAP; end = base + bcnt[b]. 1024 threads; scan on t<256.
__global__ __launch_bounds__(1024) void k_fine(const unsigned* __restrict__ sorted_c,
                                               const int* __restrict__ bcnt,
                                               int* __restrict__ offs,
                                               int* __restrict__ ends,
                                               unsigned* __restrict__ sorted_f) {
    __shared__ int cnt[BN];
    __shared__ int part[BN];
    __shared__ int cur[BN];
    const int t = threadIdx.x;
    const int b = blockIdx.x;
    if (t < BN) cnt[t] = 0;
    __syncthreads();
    const int base = b * CAP;
    const int end  = base + bcnt[b];
    for (int k = base + t; k < end; k += 1024)
        atomicAdd(&cnt[sorted_c[k] & (BN - 1)], 1);
    __syncthreads();
    int v = 0;
    if (t < BN) {
        v = cnt[t];
        part[t] = v;
    }
    __syncthreads();
    for (int d = 1; d < BN; d <<= 1) {
        const int u = (t < BN && t >= d) ? part[t - d] : 0;
        __syncthreads();
        if (t < BN) part[t] += u;
        __syncthreads();
    }
    if (t < BN) {
        const int node = b * BN + t;
        const int off = base + part[t] - v;   // exclusive within bucket (padded)
        if (node < N_NODES) { offs[node] = off; ends[node] = off + v; }
        cur[t] = off;
    }
    __syncthreads();
    for (int k = base + t; k < end; k += 1024) {
        const unsigned en = sorted_c[k];
        const int pos = atomicAdd(&cur[en & (BN - 1)], 1);
        sorted_f[pos] = en;
    }
}

// ---------------------------------------------------------------- fused
// 512 threads = 8 waves; 6250 blocks, 16 nodes each.
// B-fragments (6 x bf16x8 per phase-2 thread) loaded from global into regs
// at block start (latency hidden under phase 1). LDS = LinS + wcl ~ 7 KB.
__global__ __launch_bounds__(512, 4) void k_gather_post(
    const int*      __restrict__ offs,
    const int*      __restrict__ ends,
    const unsigned* __restrict__ sorted_f,
    const float*    __restrict__ w_comp,      // (64, 2)
    const unsigned short* __restrict__ fbs,   // (N, 64) bf16
    const unsigned short* __restrict__ wtb,   // (64, LROW) bf16 = Wcat^T padded
    const float*    __restrict__ h_bias,      // (64,)
    float*          __restrict__ out)         // (N, 64)
{
    __shared__ unsigned short LinS[NPG * LROW]; // 6.4 KB
    __shared__ float2 wcl[64];

    const int tid  = threadIdx.x;
    const int lane = tid & 63;
    const int w    = tid >> 6;
    const int r16  = lane & 15;
    const int q    = lane >> 4;

    if (tid < 64) wcl[tid] = ((const float2*)w_comp)[tid];

    // Phase-2 B fragments: issued NOW, consumed after phase 1.
    bf16x8 bfrag[6];
    if (w < 4) {
        #pragma unroll
        for (int kt = 0; kt < 6; ++kt)
            bfrag[kt] = *(const bf16x8*)&wtb[(w * 16 + r16) * LROW + kt * 32 + q * 8];
    }
    __syncthreads();   // wcl visible

    const int grp = blockIdx.x;

    // ---- Phase 1: two nodes per wave, interleaved (r17-proven) ----
    {
        const int nA = __builtin_amdgcn_readfirstlane(grp * NPG + 2 * w);
        const int nB = nA + 1;
        const int sA = __builtin_amdgcn_readfirstlane(offs[nA]);
        const int eA = __builtin_amdgcn_readfirstlane(ends[nA]);
        const int sB = __builtin_amdgcn_readfirstlane(offs[nB]);
        const int eB = __builtin_amdgcn_readfirstlane(ends[nB]);

        float aA0 = 0.f, bA0 = 0.f, aA1 = 0.f, bA1 = 0.f;
        float aB0 = 0.f, bB0 = 0.f, aB1 = 0.f, bB1 = 0.f;
        int kA = sA, kB = sB;

        while (kA + 7 < eA && kB + 7 < eB) {
            unsigned pA[8], pB[8]; float fA[8], fB[8];
            #pragma unroll
            for (int i = 0; i < 8; ++i) pA[i] = sorted_f[kA + i];  // s_load
            #pragma unroll
            for (int i = 0; i < 8; ++i) pB[i] = sorted_f[kB + i];
            #pragma unroll
            for (int i = 0; i < 8; ++i)
                fA[i] = __uint_as_float(
                    (unsigned)fbs[(size_t)((pA[i] >> 8) & 0x1FFFF) * 64 + lane] << 16);
            #pragma unroll
            for (int i = 0; i < 8; ++i)
                fB[i] = __uint_as_float(
                    (unsigned)fbs[(size_t)((pB[i] >> 8) & 0x1FFFF) * 64 + lane] << 16);
            #pragma unroll
            for (int i = 0; i < 8; ++i) {
                const float2 c = wcl[pA[i] >> 25];
                if (i & 1) { aA1 = fmaf(c.x, fA[i], aA1); bA1 = fmaf(c.y, fA[i], bA1); }
                else       { aA0 = fmaf(c.x, fA[i], aA0); bA0 = fmaf(c.y, fA[i], bA0); }
            }
            #pragma unroll
            for (int i = 0; i < 8; ++i) {
                const float2 c = wcl[pB[i] >> 25];
                if (i & 1) { aB1 = fmaf(c.x, fB[i], aB1); bB1 = fmaf(c.y, fB[i], bB1); }
                else       { aB0 = fmaf(c.x, fB[i], aB0); bB0 = fmaf(c.y, fB[i], bB0); }
            }
            kA += 8; kB += 8;
        }

        // drain node A (8/4/1 ladder)
        for (; kA + 7 < eA; kA += 8) {
            unsigned p[8]; float f[8];
            #pragma unroll
            for (int i = 0; i < 8; ++i) p[i] = sorted_f[kA + i];
            #pragma unroll
            for (int i = 0; i < 8; ++i)
                f[i] = __uint_as_float(
                    (unsigned)fbs[(size_t)((p[i] >> 8) & 0x1FFFF) * 64 + lane] << 16);
            #pragma unroll
            for (int i = 0; i < 8; ++i) {
                const float2 c = wcl[p[i] >> 25];
                if (i & 1) { aA1 = fmaf(c.x, f[i], aA1); bA1 = fmaf(c.y, f[i], bA1); }
                else       { aA0 = fmaf(c.x, f[i], aA0); bA0 = fmaf(c.y, f[i], bA0); }
            }
        }
        for (; kA + 3 < eA; kA += 4) {
            unsigned p[4]; float f[4];
            #pragma unroll
            for (int i = 0; i < 4; ++i) p[i] = sorted_f[kA + i];
            #pragma unroll
            for (int i = 0; i < 4; ++i)
                f[i] = __uint_as_float(
                    (unsigned)fbs[(size_t)((p[i] >> 8) & 0x1FFFF) * 64 + lane] << 16);
            #pragma unroll
            for (int i = 0; i < 4; ++i) {
                const float2 c = wcl[p[i] >> 25];
                if (i & 1) { aA1 = fmaf(c.x, f[i], aA1); bA1 = fmaf(c.y, f[i], bA1); }
                else       { aA0 = fmaf(c.x, f[i], aA0); bA0 = fmaf(c.y, f[i], bA0); }
            }
        }
        for (; kA < eA; ++kA) {
            const unsigned p0 = sorted_f[kA];
            const float f0 = __uint_as_float(
                (unsigned)fbs[(size_t)((p0 >> 8) & 0x1FFFF) * 64 + lane] << 16);
            const float2 c0 = wcl[p0 >> 25];
            aA0 = fmaf(c0.x, f0, aA0); bA0 = fmaf(c0.y, f0, bA0);
        }

        // drain node B
        for (; kB + 7 < eB; kB += 8) {
            unsigned p[8]; float f[8];
            #pragma unroll
            for (int i = 0; i < 8; ++i) p[i] = sorted_f[kB + i];
            #pragma unroll
            for (int i = 0; i < 8; ++i)
                f[i] = __uint_as_float(
                    (unsigned)fbs[(size_t)((p[i] >> 8) & 0x1FFFF) * 64 + lane] << 16);
            #pragma unroll
            for (int i = 0; i < 8; ++i) {
                const float2 c = wcl[p[i] >> 25];
                if (i & 1) { aB1 = fmaf(c.x, f[i], aB1); bB1 = fmaf(c.y, f[i], bB1); }
                else       { aB0 = fmaf(c.x, f[i], aB0); bB0 = fmaf(c.y, f[i], bB0); }
            }
        }
        for (; kB + 3 < eB; kB += 4) {
            unsigned p[4]; float f[4];
            #pragma unroll
            for (int i = 0; i < 4; ++i) p[i] = sorted_f[kB + i];
            #pragma unroll
            for (int i = 0; i < 4; ++i)
                f[i] = __uint_as_float(
                    (unsigned)fbs[(size_t)((p[i] >> 8) & 0x1FFFF) * 64 + lane] << 16);
            #pragma unroll
            for (int i = 0; i < 4; ++i) {
                const float2 c = wcl[p[i] >> 25];
                if (i & 1) { aB1 = fmaf(c.x, f[i], aB1); bB1 = fmaf(c.y, f[i], bB1); }
                else       { aB0 = fmaf(c.x, f[i], aB0); bB0 = fmaf(c.y, f[i], bB0); }
            }
        }
        for (; kB < eB; ++kB) {
            const unsigned p0 = sorted_f[kB];
            const float f0 = __uint_as_float(
                (unsigned)fbs[(size_t)((p0 >> 8) & 0x1FFFF) * 64 + lane] << 16);
            const float2 c0 = wcl[p0 >> 25];
            aB0 = fmaf(c0.x, f0, aB0); bB0 = fmaf(c0.y, f0, bB0);
        }

        const int slotA = 2 * w, slotB = 2 * w + 1;
        LinS[slotA * LROW + lane]       = (unsigned short)bf16_rne(aA0 + aA1);
        LinS[slotA * LROW + 64 + lane]  = (unsigned short)bf16_rne(bA0 + bA1);
        LinS[slotA * LROW + 128 + lane] = fbs[(size_t)nA * 64 + lane];
        LinS[slotB * LROW + lane]       = (unsigned short)bf16_rne(aB0 + aB1);
        LinS[slotB * LROW + 64 + lane]  = (unsigned short)bf16_rne(bB0 + bB1);
        LinS[slotB * LROW + 128 + lane] = fbs[(size_t)nB * 64 + lane];
    }
    __syncthreads();

    // ---- Phase 2: 16x64x192 via MFMA; wave w (<4) = N-tile w ----
    if (w < 4) {
        const float bv = h_bias[w * 16 + r16];
        f32x4 acc = {bv, bv, bv, bv};
        #pragma unroll
        for (int kt = 0; kt < 6; ++kt) {
            const bf16x8 a = *(const bf16x8*)&LinS[r16 * LROW + kt * 32 + q * 8];
            acc = __builtin_amdgcn_mfma_f32_16x16x32_bf16(a, bfrag[kt], acc, 0, 0, 0);
        }
        #pragma unroll
        for (int r = 0; r < 4; ++r)
            out[(size_t)(grp * NPG + q * 4 + r) * 64 + w * 16 + r16] = acc[r];
    }
}

// ---------------------------------------------------------------- launch
extern "C" void kernel_launch(void* const* d_in, const int* in_sizes, int n_in,
                              void* d_out, int out_size, void* d_ws, size_t ws_size,
                              hipStream_t stream) {
    const float* feat        = (const float*)d_in[0];
    const float* weight      = (const float*)d_in[1];
    const float* w_comp      = (const float*)d_in[2];
    const float* loop_weight = (const float*)d_in[3];
    const float* h_bias      = (const float*)d_in[4];
    const int*   src         = (const int*)d_in[5];
    const int*   dst         = (const int*)d_in[6];
    const int*   etypes      = (const int*)d_in[7];
    float* out = (float*)d_out;

    // ws layout (4B units), ~28 MB total, no aliasing:
    unsigned* sorted_c = (unsigned*)d_ws;                     // NB*CAP u32 (padded)
    unsigned* sorted_f = sorted_c + (size_t)NB * CAP;         // NB*CAP u32 (padded)
    unsigned* fbf      = sorted_f + (size_t)NB * CAP;         // 3.2M u32 (bf16 feat)
    unsigned* wtbu     = fbf + N_NODES * 32;                  // 6400 u32 (bf16 Wcat^T)
    int*      offs     = (int*)(wtbu + 64 * LROW / 2);        // N
    int*      ends     = offs + N_NODES;                      // N
    int*      bcnt     = ends + N_NODES;                      // NB

    hipMemsetAsync(bcnt, 0, NB * sizeof(int), stream);
    k_scatter_prep<<<NCH + CVT_BLOCKS + W_BLOCKS, 512, 0, stream>>>(
        src, dst, etypes, bcnt, sorted_c, feat, fbf, weight, loop_weight,
        (unsigned short*)wtbu);
    k_fine<<<NB, 1024, 0, stream>>>(sorted_c, bcnt, offs, ends, sorted_f);
    k_gather_post<<<N_GRP, 512, 0, stream>>>(offs, ends, sorted_f, w_comp,
                                             (const unsigned short*)fbf,
                                             (const unsigned short*)wtbu,
                                             h_bias, out);
}

// Round 19
// 100.602 us; speedup vs baseline: 1.9392x; 1.1316x over previous
//
#include <hip/hip_runtime.h>

// RelGraphConv basis-decomposition forward, MI355X.
//
// Input-space reformulation:
//   g[d, b, :] = sum_{e: dst_e = d} w_comp[et_e, b] * feat[src_e, :]   (b = 0,1)
//   out[d]     = [g0 | g1 | feat](192) @ Wcat(192x64) + bias,
//                Wcat = [V0; V1; W_loop]
//
// Pipeline (3 dispatches + memset):
//   memset(bcnt)  : per-bucket counts start at 0
//   k_scatter_prep: 512 thr; blocks 0..195 = coarse 391-bucket multisplit
//                   into fixed-capacity buckets; then feat->bf16; Wcat^T->bf16
//   k_fine        : per-bucket exact per-node CSR (LDS hist+scan, 1024 thr)
//   k_gather_post : phase 1 = 8 waves x 2 nodes interleaved + NEXT-BATCH
//                   ENTRY PREFETCH (SMEM leg hidden under VMEM latency);
//                   phase 2 = 16x64x192 GEMM via 24 x mfma_f32_16x16x32_bf16
//                   with B-fragments in registers (LDS ~7 KB).

constexpr int N_NODES  = 100000;
constexpr int N_EDGES  = 1600000;
constexpr int IN_FEAT  = 64;
constexpr int OUT_FEAT = 64;

constexpr int BN  = 256;                               // nodes per bucket
constexpr int NB  = (N_NODES + BN - 1) / BN;           // 391 buckets
constexpr int CAP = 4608;                              // bucket capacity (+8 sigma)
constexpr int SC_CHUNK = 8192;                         // edges per scatter block
constexpr int NCH = (N_EDGES + SC_CHUNK - 1) / SC_CHUNK;  // 196 scatter blocks
constexpr int CVT_BLOCKS = 512;                        // feat cvt blocks (512 thr)
constexpr int W_BLOCKS = 25;                           // 64*LROW/512 wtb blocks

constexpr int NPG = 16;                                // nodes per gather block
constexpr int N_GRP = N_NODES / NPG;                   // 6250 (exact)
constexpr int LROW = 200;                              // padded row (bf16)

typedef __attribute__((ext_vector_type(8))) short bf16x8;
typedef __attribute__((ext_vector_type(4))) float f32x4;

// entry pack: dst_low(8) | src(17) | etype(6)
__device__ __forceinline__ unsigned pack_entry(int d, int s, int r) {
    return (unsigned)(d & (BN - 1)) | ((unsigned)s << 8) | ((unsigned)r << 25);
}

__device__ __forceinline__ unsigned bf16_rne(float f) {
    unsigned b = __float_as_uint(f);
    b += 0x7fffu + ((b >> 16) & 1u);
    return b >> 16;
}

// ------------------------------------------------- fused scatter + convert
__global__ __launch_bounds__(512) void k_scatter_prep(
    const int* __restrict__ src, const int* __restrict__ dst,
    const int* __restrict__ et,  int* __restrict__ bcnt,
    unsigned* __restrict__ sorted_c,
    const float* __restrict__ feat, unsigned* __restrict__ fbf,
    const float* __restrict__ weight, const float* __restrict__ loop_weight,
    unsigned short* __restrict__ wtb)
{
    __shared__ int hist[NB], gb[NB], lcur[NB];
    const int b = blockIdx.x, t = threadIdx.x;

    if (b < NCH) {  // ---- multisplit scatter chunk ----
        const int cbase = b * SC_CHUNK;
        for (int i = t; i < NB; i += 512) { hist[i] = 0; lcur[i] = 0; }
        __syncthreads();
        #pragma unroll 1
        for (int k = 0; k < SC_CHUNK / 512; ++k) {
            const int e = cbase + k * 512 + t;
            if (e < N_EDGES) atomicAdd(&hist[dst[e] >> 8], 1);
        }
        __syncthreads();
        for (int i = t; i < NB; i += 512) {
            const int c = hist[i];
            gb[i] = c ? (i * CAP + atomicAdd(&bcnt[i], c)) : 0;
        }
        __syncthreads();
        #pragma unroll 1
        for (int k = 0; k < SC_CHUNK / 512; ++k) {
            const int e = cbase + k * 512 + t;
            if (e < N_EDGES) {
                const int d = dst[e];
                const int bkt = d >> 8;
                const int r = atomicAdd(&lcur[bkt], 1);
                sorted_c[gb[bkt] + r] = pack_entry(d, src[e], et[e]);
            }
        }
    } else if (b < NCH + CVT_BLOCKS) {  // ---- feat -> bf16 ----
        const int bb = b - NCH;
        const int total = N_NODES * 16;    // float4 count
        const float4* __restrict__ f4 = (const float4*)feat;
        uint2* __restrict__ o2 = (uint2*)fbf;
        for (int i = bb * 512 + t; i < total; i += CVT_BLOCKS * 512) {
            const float4 f = f4[i];
            uint2 o;
            o.x = bf16_rne(f.x) | (bf16_rne(f.y) << 16);
            o.y = bf16_rne(f.z) | (bf16_rne(f.w) << 16);
            o2[i] = o;
        }
    } else {  // ---- Wcat^T -> bf16 padded (64 x LROW) ----
        const int idx = (b - NCH - CVT_BLOCKS) * 512 + t;  // 25*512 = 12800
        const int n = idx / LROW, r = idx % LROW;
        float v = 0.0f;
        if (r < 128)      v = weight[r * 64 + n];          // V0;V1 rows contiguous
        else if (r < 192) v = loop_weight[(r - 128) * 64 + n];
        wtb[idx] = (unsigned short)bf16_rne(v);
    }
}

// ---------------------------------------------------------------- fine CSR
// base = b*CAP; end = base + bcnt[b]. 1024 threads; scan on t<256.
__global__ __launch_bounds__(1024) void k_fine(const unsigned* __restrict__ sorted_c,
                                               const int* __restrict__ bcnt,
                                               int* __restrict__ offs,
                                               int* __restrict__ ends,
                                               unsigned* __restrict__ sorted_f) {
    __shared__ int cnt[BN];
    __shared__ int part[BN];
    __shared__ int cur[BN];
    const int t = threadIdx.x;
    const int b = blockIdx.x;
    if (t < BN) cnt[t] = 0;
    __syncthreads();
    const int base = b * CAP;
    const int end  = base + bcnt[b];
    for (int k = base + t; k < end; k += 1024)
        atomicAdd(&cnt[sorted_c[k] & (BN - 1)], 1);
    __syncthreads();
    int v = 0;
    if (t < BN) {
        v = cnt[t];
        part[t] = v;
    }
    __syncthreads();
    for (int d = 1; d < BN; d <<= 1) {
        const int u = (t < BN && t >= d) ? part[t - d] : 0;
        __syncthreads();
        if (t < BN) part[t] += u;
        __syncthreads();
    }
    if (t < BN) {
        const int node = b * BN + t;
        const int off = base + part[t] - v;   // exclusive within bucket (padded)
        if (node < N_NODES) { offs[node] = off; ends[node] = off + v; }
        cur[t] = off;
    }
    __syncthreads();
    for (int k = base + t; k < end; k += 1024) {
        const unsigned en = sorted_c[k];
        const int pos = atomicAdd(&cur[en & (BN - 1)], 1);
        sorted_f[pos] = en;
    }
}

// ---------------------------------------------------------------- fused
// 512 threads = 8 waves; 6250 blocks, 16 nodes each.
// Phase 1: interleaved A/B with next-batch entry prefetch: while the current
//          batch's 16 feat loads are in flight, the next batch's 16 entries
//          are fetched (no data dependency) -- hides the SMEM leg.
// Phase 2: waves 0-3 = N-tile w; 6 mfma 16x16x32 with B-fragments in regs.
__global__ __launch_bounds__(512, 4) void k_gather_post(
    const int*      __restrict__ offs,
    const int*      __restrict__ ends,
    const unsigned* __restrict__ sorted_f,
    const float*    __restrict__ w_comp,      // (64, 2)
    const unsigned short* __restrict__ fbs,   // (N, 64) bf16
    const unsigned short* __restrict__ wtb,   // (64, LROW) bf16 = Wcat^T padded
    const float*    __restrict__ h_bias,      // (64,)
    float*          __restrict__ out)         // (N, 64)
{
    __shared__ unsigned short LinS[NPG * LROW]; // 6.4 KB
    __shared__ float2 wcl[64];

    const int tid  = threadIdx.x;
    const int lane = tid & 63;
    const int w    = tid >> 6;
    const int r16  = lane & 15;
    const int q    = lane >> 4;

    if (tid < 64) wcl[tid] = ((const float2*)w_comp)[tid];

    // Phase-2 B fragments: issued NOW, consumed after phase 1.
    bf16x8 bfrag[6];
    if (w < 4) {
        #pragma unroll
        for (int kt = 0; kt < 6; ++kt)
            bfrag[kt] = *(const bf16x8*)&wtb[(w * 16 + r16) * LROW + kt * 32 + q * 8];
    }
    __syncthreads();   // wcl visible

    const int grp = blockIdx.x;

    // ---- Phase 1: two nodes per wave, interleaved + entry prefetch ----
    {
        const int nA = __builtin_amdgcn_readfirstlane(grp * NPG + 2 * w);
        const int nB = nA + 1;
        const int sA = __builtin_amdgcn_readfirstlane(offs[nA]);
        const int eA = __builtin_amdgcn_readfirstlane(ends[nA]);
        const int sB = __builtin_amdgcn_readfirstlane(offs[nB]);
        const int eB = __builtin_amdgcn_readfirstlane(ends[nB]);
        const unsigned short fvA = fbs[(size_t)nA * 64 + lane];  // early issue
        const unsigned short fvB = fbs[(size_t)nB * 64 + lane];

        float aA0 = 0.f, bA0 = 0.f, aA1 = 0.f, bA1 = 0.f;
        float aB0 = 0.f, bB0 = 0.f, aB1 = 0.f, bB1 = 0.f;
        int kA = sA, kB = sB;

        if (kA + 7 < eA && kB + 7 < eB) {
            unsigned pA[8], pB[8];
            #pragma unroll
            for (int i = 0; i < 8; ++i) pA[i] = sorted_f[kA + i];   // s_load
            #pragma unroll
            for (int i = 0; i < 8; ++i) pB[i] = sorted_f[kB + i];
            #pragma unroll 1
            while (true) {
                float fA[8], fB[8];
                #pragma unroll
                for (int i = 0; i < 8; ++i)
                    fA[i] = __uint_as_float(
                        (unsigned)fbs[(size_t)((pA[i] >> 8) & 0x1FFFF) * 64 + lane] << 16);
                #pragma unroll
                for (int i = 0; i < 8; ++i)
                    fB[i] = __uint_as_float(
                        (unsigned)fbs[(size_t)((pB[i] >> 8) & 0x1FFFF) * 64 + lane] << 16);
                const bool more = (kA + 15 < eA) && (kB + 15 < eB);
                unsigned qA[8], qB[8];
                if (more) {   // prefetch next batch entries under VMEM latency
                    #pragma unroll
                    for (int i = 0; i < 8; ++i) qA[i] = sorted_f[kA + 8 + i];
                    #pragma unroll
                    for (int i = 0; i < 8; ++i) qB[i] = sorted_f[kB + 8 + i];
                }
                #pragma unroll
                for (int i = 0; i < 8; ++i) {
                    const float2 c = wcl[pA[i] >> 25];
                    if (i & 1) { aA1 = fmaf(c.x, fA[i], aA1); bA1 = fmaf(c.y, fA[i], bA1); }
                    else       { aA0 = fmaf(c.x, fA[i], aA0); bA0 = fmaf(c.y, fA[i], bA0); }
                }
                #pragma unroll
                for (int i = 0; i < 8; ++i) {
                    const float2 c = wcl[pB[i] >> 25];
                    if (i & 1) { aB1 = fmaf(c.x, fB[i], aB1); bB1 = fmaf(c.y, fB[i], bB1); }
                    else       { aB0 = fmaf(c.x, fB[i], aB0); bB0 = fmaf(c.y, fB[i], bB0); }
                }
                kA += 8; kB += 8;
                if (!more) break;
                #pragma unroll
                for (int i = 0; i < 8; ++i) { pA[i] = qA[i]; pB[i] = qB[i]; }
            }
        }

        // drain node A (8/4/1 ladder)
        for (; kA + 7 < eA; kA += 8) {
            unsigned p[8]; float f[8];
            #pragma unroll
            for (int i = 0; i < 8; ++i) p[i] = sorted_f[kA + i];
            #pragma unroll
            for (int i = 0; i < 8; ++i)
                f[i] = __uint_as_float(
                    (unsigned)fbs[(size_t)((p[i] >> 8) & 0x1FFFF) * 64 + lane] << 16);
            #pragma unroll
            for (int i = 0; i < 8; ++i) {
                const float2 c = wcl[p[i] >> 25];
                if (i & 1) { aA1 = fmaf(c.x, f[i], aA1); bA1 = fmaf(c.y, f[i], bA1); }
                else       { aA0 = fmaf(c.x, f[i], aA0); bA0 = fmaf(c.y, f[i], bA0); }
            }
        }
        for (; kA + 3 < eA; kA += 4) {
            unsigned p[4]; float f[4];
            #pragma unroll
            for (int i = 0; i < 4; ++i) p[i] = sorted_f[kA + i];
            #pragma unroll
            for (int i = 0; i < 4; ++i)
                f[i] = __uint_as_float(
                    (unsigned)fbs[(size_t)((p[i] >> 8) & 0x1FFFF) * 64 + lane] << 16);
            #pragma unroll
            for (int i = 0; i < 4; ++i) {
                const float2 c = wcl[p[i] >> 25];
                if (i & 1) { aA1 = fmaf(c.x, f[i], aA1); bA1 = fmaf(c.y, f[i], bA1); }
                else       { aA0 = fmaf(c.x, f[i], aA0); bA0 = fmaf(c.y, f[i], bA0); }
            }
        }
        for (; kA < eA; ++kA) {
            const unsigned p0 = sorted_f[kA];
            const float f0 = __uint_as_float(
                (unsigned)fbs[(size_t)((p0 >> 8) & 0x1FFFF) * 64 + lane] << 16);
            const float2 c0 = wcl[p0 >> 25];
            aA0 = fmaf(c0.x, f0, aA0); bA0 = fmaf(c0.y, f0, bA0);
        }

        // drain node B
        for (; kB + 7 < eB; kB += 8) {
            unsigned p[8]; float f[8];
            #pragma unroll
            for (int i = 0; i < 8; ++i) p[i] = sorted_f[kB + i];
            #pragma unroll
            for (int i = 0; i < 8; ++i)
                f[i] = __uint_as_float(
                    (unsigned)fbs[(size_t)((p[i] >> 8) & 0x1FFFF) * 64 + lane] << 16);
            #pragma unroll
            for (int i = 0; i < 8; ++i) {
                const float2 c = wcl[p[i] >> 25];
                if (i & 1) { aB1 = fmaf(c.x, f[i], aB1); bB1 = fmaf(c.y, f[i], bB1); }
                else       { aB0 = fmaf(c.x, f[i], aB0); bB0 = fmaf(c.y, f[i], bB0); }
            }
        }
        for (; kB + 3 < eB; kB += 4) {
            unsigned p[4]; float f[4];
            #pragma unroll
            for (int i = 0; i < 4; ++i) p[i] = sorted_f[kB + i];
            #pragma unroll
            for (int i = 0; i < 4; ++i)
                f[i] = __uint_as_float(
                    (unsigned)fbs[(size_t)((p[i] >> 8) & 0x1FFFF) * 64 + lane] << 16);
            #pragma unroll
            for (int i = 0; i < 4; ++i) {
                const float2 c = wcl[p[i] >> 25];
                if (i & 1) { aB1 = fmaf(c.x, f[i], aB1); bB1 = fmaf(c.y, f[i], bB1); }
                else       { aB0 = fmaf(c.x, f[i], aB0); bB0 = fmaf(c.y, f[i], bB0); }
            }
        }
        for (; kB < eB; ++kB) {
            const unsigned p0 = sorted_f[kB];
            const float f0 = __uint_as_float(
                (unsigned)fbs[(size_t)((p0 >> 8) & 0x1FFFF) * 64 + lane] << 16);
            const float2 c0 = wcl[p0 >> 25];
            aB0 = fmaf(c0.x, f0, aB0); bB0 = fmaf(c0.y, f0, bB0);
        }

        const int slotA = 2 * w, slotB = 2 * w + 1;
        LinS[slotA * LROW + lane]       = (unsigned short)bf16_rne(aA0 + aA1);
        LinS[slotA * LROW + 64 + lane]  = (unsigned short)bf16_rne(bA0 + bA1);
        LinS[slotA * LROW + 128 + lane] = fvA;
        LinS[slotB * LROW + lane]       = (unsigned short)bf16_rne(aB0 + aB1);
        LinS[slotB * LROW + 64 + lane]  = (unsigned short)bf16_rne(bB0 + bB1);
        LinS[slotB * LROW + 128 + lane] = fvB;
    }
    __syncthreads();

    // ---- Phase 2: 16x64x192 via MFMA; wave w (<4) = N-tile w ----
    if (w < 4) {
        const float bv = h_bias[w * 16 + r16];
        f32x4 acc = {bv, bv, bv, bv};
        #pragma unroll
        for (int kt = 0; kt < 6; ++kt) {
            const bf16x8 a = *(const bf16x8*)&LinS[r16 * LROW + kt * 32 + q * 8];
            acc = __builtin_amdgcn_mfma_f32_16x16x32_bf16(a, bfrag[kt], acc, 0, 0, 0);
        }
        #pragma unroll
        for (int r = 0; r < 4; ++r)
            out[(size_t)(grp * NPG + q * 4 + r) * 64 + w * 16 + r16] = acc[r];
    }
}

// ---------------------------------------------------------------- launch
extern "C" void kernel_launch(void* const* d_in, const int* in_sizes, int n_in,
                              void* d_out, int out_size, void* d_ws, size_t ws_size,
                              hipStream_t stream) {
    const float* feat        = (const float*)d_in[0];
    const float* weight      = (const float*)d_in[1];
    const float* w_comp      = (const float*)d_in[2];
    const float* loop_weight = (const float*)d_in[3];
    const float* h_bias      = (const float*)d_in[4];
    const int*   src         = (const int*)d_in[5];
    const int*   dst         = (const int*)d_in[6];
    const int*   etypes      = (const int*)d_in[7];
    float* out = (float*)d_out;

    // ws layout (4B units), ~28 MB total, no aliasing:
    unsigned* sorted_c = (unsigned*)d_ws;                     // NB*CAP u32 (padded)
    unsigned* sorted_f = sorted_c + (size_t)NB * CAP;         // NB*CAP u32 (padded)
    unsigned* fbf      = sorted_f + (size_t)NB * CAP;         // 3.2M u32 (bf16 feat)
    unsigned* wtbu     = fbf + N_NODES * 32;                  // 6400 u32 (bf16 Wcat^T)
    int*      offs     = (int*)(wtbu + 64 * LROW / 2);        // N
    int*      ends     = offs + N_NODES;                      // N
    int*      bcnt     = ends + N_NODES;                      // NB

    hipMemsetAsync(bcnt, 0, NB * sizeof(int), stream);
    k_scatter_prep<<<NCH + CVT_BLOCKS + W_BLOCKS, 512, 0, stream>>>(
        src, dst, etypes, bcnt, sorted_c, feat, fbf, weight, loop_weight,
        (unsigned short*)wtbu);
    k_fine<<<NB, 1024, 0, stream>>>(sorted_c, bcnt, offs, ends, sorted_f);
    k_gather_post<<<N_GRP, 512, 0, stream>>>(offs, ends, sorted_f, w_comp,
                                             (const unsigned short*)fbf,
                                             (const unsigned short*)wtbu,
                                             h_bias, out);
}